// Round 13
// baseline (116.749 us; speedup 1.0000x reference)
//
#include <hip/hip_runtime.h>
#include <hip/hip_bf16.h>

// MHA layer B=2, S=2048, DM=1024, H=16, DK=DV=64 on gfx950.
// conv fp32->bf16 (separate, HBM-floor) -> weight transposes -> 3 proj GEMMs
// (pure-bf16 m97, A-tile XCD-grouped) -> flash attention (wave = 64q x 64kv-half)
// -> out GEMM (128x64). Conv fusion reverted: 3x proven latency-bound (r4/r5/r12).

using bf16 = __hip_bfloat16;
typedef __attribute__((ext_vector_type(4))) float f32x4;
typedef __attribute__((ext_vector_type(8))) short bf16x8;

__device__ __forceinline__ void gload_lds16(const void* gsrc, void* ldst) {
    __builtin_amdgcn_global_load_lds(
        (const __attribute__((address_space(1))) void*)gsrc,
        (__attribute__((address_space(3))) void*)ldst,
        16, 0, 0);
}

__device__ __forceinline__ float fexp2(float x) {
    float r; asm("v_exp_f32 %0, %1" : "=v"(r) : "v"(x)); return r;
}

__device__ __forceinline__ unsigned cvtpk(float a, float b) {
    unsigned d; asm("v_cvt_pk_bf16_f32 %0, %1, %2" : "=v"(d) : "v"(a), "v"(b));
    return d;
}

__device__ __forceinline__ void pls32(unsigned &a, unsigned &b) {
    asm("v_permlane32_swap_b32 %0, %1" : "+v"(a), "+v"(b));
}
__device__ __forceinline__ void pls16(unsigned &a, unsigned &b) {
    asm("v_permlane16_swap_b32 %0, %1" : "+v"(a), "+v"(b));
}

__device__ __forceinline__ unsigned pack2bf(float a, float b) {
    unsigned short ua = __builtin_bit_cast(unsigned short, __float2bfloat16(a));
    unsigned short ub = __builtin_bit_cast(unsigned short, __float2bfloat16(b));
    return (unsigned)ua | ((unsigned)ub << 16);
}

// ---------------- fp32 -> bf16, three tensors (z) ----------------
__global__ void conv3_kernel(const float* __restrict__ X0, const float* __restrict__ X1,
                             const float* __restrict__ X2,
                             bf16* __restrict__ O0, bf16* __restrict__ O1, bf16* __restrict__ O2,
                             int n4) {
    int z = blockIdx.z;
    const float* in = z == 0 ? X0 : (z == 1 ? X1 : X2);
    bf16* out = z == 0 ? O0 : (z == 1 ? O1 : O2);
    int idx = blockIdx.x * blockDim.x + threadIdx.x;
    int stride = gridDim.x * blockDim.x;
    for (int i = idx; i < n4; i += stride) {
        float4 v = reinterpret_cast<const float4*>(in)[i];
        reinterpret_cast<uint2*>(out)[i] = make_uint2(pack2bf(v.x, v.y), pack2bf(v.z, v.w));
    }
}

// ---------------- 1024x1024 fp32 -> bf16 transpose, four weights (z) ----------------
__global__ void transpose4_kernel(const float* __restrict__ W0, const float* __restrict__ W1,
                                  const float* __restrict__ W2, const float* __restrict__ W3,
                                  bf16* __restrict__ T0, bf16* __restrict__ T1,
                                  bf16* __restrict__ T2, bf16* __restrict__ T3) {
    int z = blockIdx.z;
    const float* W = z == 0 ? W0 : (z == 1 ? W1 : (z == 2 ? W2 : W3));
    bf16* WT = z == 0 ? T0 : (z == 1 ? T1 : (z == 2 ? T2 : T3));
    __shared__ float t[32][33];
    int bx = blockIdx.x * 32, by = blockIdx.y * 32;
    int x = threadIdx.x, y = threadIdx.y;
    #pragma unroll
    for (int i = 0; i < 4; ++i)
        t[y + 8*i][x] = W[(size_t)(by + y + 8*i) * 1024 + bx + x];
    __syncthreads();
    #pragma unroll
    for (int i = 0; i < 4; ++i)
        WT[(size_t)(bx + y + 8*i) * 1024 + by + x] = __float2bfloat16(t[x][y + 8*i]);
}

// ---------------- GEMM: C[4096,NTOT] = A[4096,1024] @ BT^T + bias ----------------
// m97 structure: 128xNTILE tile, BK=64, single-buffered LDS, global_load_lds w16,
// XOR-swizzled rows via pre-swizzled global src, two barriers per K-step.
// mode = mode_base+z: 0 bf16 out *log2e/sqrt2 | 1 bf16 | 2 bf16 -> Vt[b][h][dv][s] | 3 fp32
template<int NTILE>
__global__ __launch_bounds__(256, 3)
void gemm_bt(const bf16* __restrict__ A0, const bf16* __restrict__ A1, const bf16* __restrict__ A2,
             const bf16* __restrict__ B0, const bf16* __restrict__ B1, const bf16* __restrict__ B2,
             const float* __restrict__ bi0, const float* __restrict__ bi1, const float* __restrict__ bi2,
             void* __restrict__ O0, void* __restrict__ O1, void* __restrict__ O2,
             int mode_base)
{
    const int f = blockIdx.x;
    int x, y, z;
    if (NTILE == 128) {
        const int s = f >> 3;
        y = s & 7;
        const int t = (f & 7) + 8 * (s >> 3);
        x = t & 31; z = t >> 5;
    } else {
        const int s = f >> 3;
        y = s & 15;
        x = (f & 7) + 8 * (s >> 4);
        z = 0;
    }
    const bf16* A  = z == 0 ? A0 : (z == 1 ? A1 : A2);
    const bf16* BT = z == 0 ? B0 : (z == 1 ? B1 : B2);
    const float* bias = z == 0 ? bi0 : (z == 1 ? bi1 : bi2);
    void* Cout = z == 0 ? O0 : (z == 1 ? O1 : O2);
    const int mode = mode_base + z;

    constexpr int MF = (NTILE == 128) ? 4 : 2;
    __shared__ __align__(16) char Abuf[16384];
    __shared__ __align__(16) char Bbuf[NTILE * 128];
    const int tid = threadIdx.x;
    const int wave = tid >> 6, lane = tid & 63;
    const int g = lane >> 4, ln = lane & 15;
    const int m0 = x * 128, n0 = y * NTILE;
    const int wm = (NTILE == 128) ? (wave >> 1) * 64 : wave * 32;
    const int wn = (NTILE == 128) ? (wave & 1) * 64 : 0;
    const int lnsw = (ln & 7) << 4;

    f32x4 acc[MF][4] = {};

    for (int k0 = 0; k0 < 1024; k0 += 64) {
        __syncthreads();
        #pragma unroll
        for (int rd = 0; rd < 4; ++rd) {
            int row = rd * 32 + (tid >> 3);
            int src = ((tid & 7) * 16) ^ (((tid >> 3) & 7) << 4);
            gload_lds16((const char*)(A + (size_t)(m0 + row) * 1024 + k0) + src,
                        Abuf + rd * 4096 + tid * 16);
        }
        #pragma unroll
        for (int rd = 0; rd < NTILE / 32; ++rd) {
            int row = rd * 32 + (tid >> 3);
            int src = ((tid & 7) * 16) ^ (((tid >> 3) & 7) << 4);
            gload_lds16((const char*)(BT + (size_t)(n0 + row) * 1024 + k0) + src,
                        Bbuf + rd * 4096 + tid * 16);
        }
        __syncthreads();
        #pragma unroll
        for (int kk = 0; kk < 2; ++kk) {
            bf16x8 af[MF], bfr[4];
            #pragma unroll
            for (int mf = 0; mf < MF; ++mf)
                af[mf] = *(const bf16x8*)&Abuf[(wm + mf*16 + ln) * 128 + ((kk*64 + g*16) ^ lnsw)];
            #pragma unroll
            for (int nf = 0; nf < 4; ++nf)
                bfr[nf] = *(const bf16x8*)&Bbuf[(wn + nf*16 + ln) * 128 + ((kk*64 + g*16) ^ lnsw)];
            #pragma unroll
            for (int mf = 0; mf < MF; ++mf)
                #pragma unroll
                for (int nf = 0; nf < 4; ++nf)
                    acc[mf][nf] = __builtin_amdgcn_mfma_f32_16x16x32_bf16(af[mf], bfr[nf], acc[mf][nf], 0, 0, 0);
        }
    }

    const float scl = (mode == 0) ? (0.70710678118654752f * 1.44269504088896340f) : 1.0f;
    #pragma unroll
    for (int mf = 0; mf < MF; ++mf) {
        #pragma unroll
        for (int nf = 0; nf < 4; ++nf) {
            int col = n0 + wn + nf*16 + ln;
            float bv = bias[col];
            #pragma unroll
            for (int r = 0; r < 4; ++r) {
                int row = m0 + wm + mf*16 + g*4 + r;
                float v = (acc[mf][nf][r] + bv) * scl;
                if (mode == 0 || mode == 1) {
                    ((bf16*)Cout)[(size_t)row * 1024 + col] = __float2bfloat16(v);
                } else if (mode == 2) {
                    int b = row >> 11, ss = row & 2047;
                    int hh = col >> 6, dv = col & 63;
                    ((bf16*)Cout)[(((size_t)(b*16 + hh) * 64 + dv) << 11) + ss] = __float2bfloat16(v);
                } else {
                    ((float*)Cout)[(size_t)row * 1024 + col] = v;
                }
            }
        }
    }
}

// ---------------- flash attention: wave = (q-half, kv-half) ----------------
// qh_: [B*S][1024] bf16 pre-scaled by log2e/sqrt(2); kh: [B*S][1024] bf16;
// vt: [B][H][64][2048] bf16; aout: [B*S][1024] bf16.
// Block: 128 q x 128 kv/iter (16 iters), 4 waves: wave=(qh<<1|kvh), each 64q x 64kv.
// K: [128][128B] swz (row&7)<<4; V: [64dv][256B] swz col16^=(row&15).
// kv-halves combined once at end through dead K-LDS. lsum in VALU.
__global__ __launch_bounds__(256, 2)
void attn_kernel(const bf16* __restrict__ qh_, const bf16* __restrict__ kh,
                 const bf16* __restrict__ vt, bf16* __restrict__ aout)
{
    __shared__ __align__(16) bf16 Kls[2][128 * 64];
    __shared__ __align__(16) bf16 Vls[2][64 * 128];
    const int f = blockIdx.x;
    const int xcd = f & 7, s = f >> 3, i = s & 15, ghi = s >> 4;
    const int bh = xcd + 8 * ghi;
    const int b = bh >> 4, h = bh & 15;
    const int q0 = i * 128;

    const int tid = threadIdx.x;
    const int wave = tid >> 6, lane = tid & 63;
    const int qh = wave >> 1, kvh = wave & 1;
    const int g = lane >> 4, ln = lane & 15;
    const int srow = lane >> 3;
    const int scol = ((lane & 7) * 16) ^ ((srow & 7) << 4);
    const int lnsw = (ln & 7) << 4;
    const int vrow_in = lane >> 4, vcol16 = lane & 15;

    const bf16* kbase = kh + (size_t)(b * 2048) * 1024 + h * 64;
    const bf16* vbase = vt + (size_t)bh * 64 * 2048;
    char* Kb = (char*)&Kls[0][0];
    char* Vb = (char*)&Vls[0][0];

    // Q fragments: 64 q rows per wave
    bf16x8 qf[4][2];
    #pragma unroll
    for (int nf = 0; nf < 4; ++nf) {
        const bf16* qrow = qh_ + (size_t)(b*2048 + q0 + qh*64 + nf*16 + ln) * 1024 + h*64;
        qf[nf][0] = *(const bf16x8*)(qrow + g*8);
        qf[nf][1] = *(const bf16x8*)(qrow + 32 + g*8);
    }

    // stage 128-kv tile: K 16KB (16 chunks of 8 rows), V 16KB (16 chunks of 4x256B rows)
    auto stageKV = [&](int kv0, int buf) {
        #pragma unroll
        for (int c2 = 0; c2 < 4; ++c2) {
            int c = wave * 4 + c2;
            int krow = c * 8 + srow;
            gload_lds16((const char*)(kbase + (size_t)(kv0 + krow) * 1024) + scol,
                        Kb + buf * 16384 + c * 1024);
        }
        #pragma unroll
        for (int c2 = 0; c2 < 4; ++c2) {
            int c = wave * 4 + c2;
            int vrow = c * 4 + vrow_in;
            int sc16 = vcol16 ^ (vrow & 15);
            gload_lds16((const char*)(vbase + (size_t)vrow * 2048 + kv0) + sc16 * 16,
                        Vb + buf * 16384 + c * 1024);
        }
    };

    stageKV(0, 0);

    f32x4 oacc[4][4] = {};
    float lsum[4] = {0.f, 0.f, 0.f, 0.f};
    union PU { unsigned u[4]; bf16x8 v; };

    for (int t = 0; t < 16; ++t) {
        const int cur = t & 1;
        if (t < 15) {
            stageKV((t + 1) * 128, cur ^ 1);
            asm volatile("s_waitcnt vmcnt(8)\n\ts_barrier" ::: "memory");
        } else {
            asm volatile("s_waitcnt vmcnt(0)\n\ts_barrier" ::: "memory");
        }
        __builtin_amdgcn_sched_barrier(0);

        const char* Kc = Kb + cur * 16384;
        const char* Vc = Vb + cur * 16384;

        // QK: S^T rows = local kv (wave's 64-half), cols = q (64 over 4 nf)
        f32x4 sac[4][4] = {};
        __builtin_amdgcn_s_setprio(1);
        #pragma unroll
        for (int kk = 0; kk < 2; ++kk) {
            bf16x8 kf[4];
            #pragma unroll
            for (int mf = 0; mf < 4; ++mf) {
                int row = kvh*64 + mf*16 + ln;
                kf[mf] = *(const bf16x8*)(Kc + row * 128 + ((kk*64 + g*16) ^ lnsw));
            }
            #pragma unroll
            for (int mf = 0; mf < 4; ++mf)
                #pragma unroll
                for (int nf = 0; nf < 4; ++nf)
                    sac[mf][nf] = __builtin_amdgcn_mfma_f32_16x16x32_bf16(kf[mf], qf[nf][kk], sac[mf][nf], 0, 0, 0);
        }
        __builtin_amdgcn_s_setprio(0);
        __builtin_amdgcn_sched_barrier(0);

        // SM: P = exp2(s), lsum += rows, pack, butterfly -> pf[nf][kk]
        PU pf[4][2];
        #pragma unroll
        for (int nf = 0; nf < 4; ++nf) {
            unsigned w[4][2];
            #pragma unroll
            for (int mf = 0; mf < 4; ++mf) {
                float e0 = fexp2(sac[mf][nf][0]);
                float e1 = fexp2(sac[mf][nf][1]);
                float e2 = fexp2(sac[mf][nf][2]);
                float e3 = fexp2(sac[mf][nf][3]);
                lsum[nf] += (e0 + e1) + (e2 + e3);
                w[mf][0] = cvtpk(e0, e1);
                w[mf][1] = cvtpk(e2, e3);
            }
            #pragma unroll
            for (int kk = 0; kk < 2; ++kk) {
                #pragma unroll
                for (int rp = 0; rp < 2; ++rp) {
                    unsigned a = w[2*kk][rp], bb = w[2*kk + 1][rp];
                    pls32(a, bb);
                    pls16(a, bb);
                    pf[nf][kk].u[rp] = a;
                    pf[nf][kk].u[2 + rp] = bb;
                }
            }
        }

        // PV: O^T[64dv][64q] += V^T(wave's kv-half) * P
        __builtin_amdgcn_s_setprio(1);
        #pragma unroll
        for (int kk = 0; kk < 2; ++kk) {
            bf16x8 vf[4];
            #pragma unroll
            for (int mf = 0; mf < 4; ++mf) {
                int row = mf*16 + ln;
                vf[mf] = *(const bf16x8*)(Vc + row * 256 + (((kvh*8 + kk*4 + g) ^ ln) << 4));
            }
            #pragma unroll
            for (int mf = 0; mf < 4; ++mf)
                #pragma unroll
                for (int nf = 0; nf < 4; ++nf)
                    oacc[mf][nf] = __builtin_amdgcn_mfma_f32_16x16x32_bf16(vf[mf], pf[nf][kk].v, oacc[mf][nf], 0, 0, 0);
        }
        __builtin_amdgcn_s_setprio(0);
        __builtin_amdgcn_sched_barrier(0);
        asm volatile("s_waitcnt lgkmcnt(0)\n\ts_barrier" ::: "memory");
    }

    // reduce lsum over g (kv spread within wave), then combine kv-halves via LDS
    #pragma unroll
    for (int nf = 0; nf < 4; ++nf) {
        float l = lsum[nf];
        l += __shfl_xor(l, 16);
        l += __shfl_xor(l, 32);
        lsum[nf] = l;
    }
    __syncthreads();
    float* Lb = (float*)Vb;
    if (kvh == 1) {
        #pragma unroll
        for (int mf = 0; mf < 4; ++mf)
            #pragma unroll
            for (int nf = 0; nf < 4; ++nf)
                *(f32x4*)(Kb + qh * 16384 + (mf*4 + nf) * 1024 + lane * 16) = oacc[mf][nf];
        #pragma unroll
        for (int nf = 0; nf < 4; ++nf)
            Lb[qh * 256 + nf * 64 + lane] = lsum[nf];
    }
    __syncthreads();
    if (kvh == 0) {
        #pragma unroll
        for (int nf = 0; nf < 4; ++nf) {
            float inv = 1.0f / (lsum[nf] + Lb[qh * 256 + nf * 64 + lane]);
            int q = q0 + qh*64 + nf*16 + ln;
            bf16* orow = aout + (size_t)(b*2048 + q) * 1024 + h * 64;
            #pragma unroll
            for (int mf = 0; mf < 4; ++mf) {
                f32x4 o2 = *(const f32x4*)(Kb + qh * 16384 + (mf*4 + nf) * 1024 + lane * 16);
                float v0 = (oacc[mf][nf][0] + o2[0]) * inv;
                float v1 = (oacc[mf][nf][1] + o2[1]) * inv;
                float v2 = (oacc[mf][nf][2] + o2[2]) * inv;
                float v3 = (oacc[mf][nf][3] + o2[3]) * inv;
                *(uint2*)(orow + mf*16 + g*4) = make_uint2(pack2bf(v0, v1), pack2bf(v2, v3));
            }
        }
    }
}

// ---------------- host ----------------
extern "C" void kernel_launch(void* const* d_in, const int* in_sizes, int n_in,
                              void* d_out, int out_size, void* d_ws, size_t ws_size,
                              hipStream_t stream)
{
    const float* Q  = (const float*)d_in[0];
    const float* K  = (const float*)d_in[1];
    const float* V  = (const float*)d_in[2];
    const float* Wq = (const float*)d_in[3];
    const float* bq = (const float*)d_in[4];
    const float* Wk = (const float*)d_in[5];
    const float* bk = (const float*)d_in[6];
    const float* Wv = (const float*)d_in[7];
    const float* bv = (const float*)d_in[8];
    const float* Wo = (const float*)d_in[9];
    const float* bo = (const float*)d_in[10];

    char* ws = (char*)d_ws;
    const size_t MB = 1024 * 1024;
    bf16* Qbf  = (bf16*)(ws + 0);
    bf16* Kbf  = (bf16*)(ws + 8*MB);
    bf16* Vbf  = (bf16*)(ws + 16*MB);
    bf16* WqT  = (bf16*)(ws + 24*MB);
    bf16* WkT  = (bf16*)(ws + 26*MB);
    bf16* WvT  = (bf16*)(ws + 28*MB);
    bf16* WoT  = (bf16*)(ws + 30*MB);
    bf16* qhp  = (bf16*)(ws + 32*MB);
    bf16* khp  = (bf16*)(ws + 40*MB);
    bf16* vtp  = (bf16*)(ws + 48*MB);
    bf16* aout = (bf16*)(ws + 0);      // alias Qbf (dead after projections)

    const int n4 = (2 * 2048 * 1024) / 4;
    conv3_kernel<<<dim3(512, 1, 3), 256, 0, stream>>>(Q, K, V, Qbf, Kbf, Vbf, n4);

    transpose4_kernel<<<dim3(32, 32, 4), dim3(32, 8), 0, stream>>>(Wq, Wk, Wv, Wo, WqT, WkT, WvT, WoT);

    gemm_bt<128><<<768, 256, 0, stream>>>(Qbf, Kbf, Vbf, WqT, WkT, WvT,
                                          bq, bk, bv, qhp, khp, vtp, 0);

    attn_kernel<<<512, 256, 0, stream>>>(qhp, khp, vtp, aout);

    gemm_bt<64><<<512, 256, 0, stream>>>(aout, aout, aout, WoT, WoT, WoT,
                                         bo, bo, bo, d_out, d_out, d_out, 3);
}

// Round 14
// 112.291 us; speedup vs baseline: 1.0397x; 1.0397x over previous
//
#include <hip/hip_runtime.h>
#include <hip/hip_bf16.h>

// MHA layer B=2, S=2048, DM=1024, H=16, DK=DV=64 on gfx950.
// prep (conv fp32->bf16 z=0-2 + weight transpose z=3-6, ONE launch) ->
// 3 proj GEMMs (pure-bf16 m97, A-tile XCD-grouped) ->
// flash attention (r8 best: 128kv staging, SM hoisted for both halves) ->
// out GEMM (128x64 tiles).

using bf16 = __hip_bfloat16;
typedef __attribute__((ext_vector_type(4))) float f32x4;
typedef __attribute__((ext_vector_type(8))) short bf16x8;

__device__ __forceinline__ void gload_lds16(const void* gsrc, void* ldst) {
    __builtin_amdgcn_global_load_lds(
        (const __attribute__((address_space(1))) void*)gsrc,
        (__attribute__((address_space(3))) void*)ldst,
        16, 0, 0);
}

__device__ __forceinline__ float fexp2(float x) {
    float r; asm("v_exp_f32 %0, %1" : "=v"(r) : "v"(x)); return r;
}

__device__ __forceinline__ unsigned cvtpk(float a, float b) {
    unsigned d; asm("v_cvt_pk_bf16_f32 %0, %1, %2" : "=v"(d) : "v"(a), "v"(b));
    return d;
}

__device__ __forceinline__ void pls32(unsigned &a, unsigned &b) {
    asm("v_permlane32_swap_b32 %0, %1" : "+v"(a), "+v"(b));
}
__device__ __forceinline__ void pls16(unsigned &a, unsigned &b) {
    asm("v_permlane16_swap_b32 %0, %1" : "+v"(a), "+v"(b));
}

__device__ __forceinline__ unsigned pack2bf(float a, float b) {
    unsigned short ua = __builtin_bit_cast(unsigned short, __float2bfloat16(a));
    unsigned short ub = __builtin_bit_cast(unsigned short, __float2bfloat16(b));
    return (unsigned)ua | ((unsigned)ub << 16);
}

// ---------------- prep: z=0..2 conv fp32->bf16 (grid-stride), z=3..6 transpose ----------------
__global__ void prep_kernel(const float* __restrict__ X0, const float* __restrict__ X1,
                            const float* __restrict__ X2,
                            bf16* __restrict__ O0, bf16* __restrict__ O1, bf16* __restrict__ O2,
                            const float* __restrict__ W0, const float* __restrict__ W1,
                            const float* __restrict__ W2, const float* __restrict__ W3,
                            bf16* __restrict__ T0, bf16* __restrict__ T1,
                            bf16* __restrict__ T2, bf16* __restrict__ T3,
                            int n4) {
    const int z = blockIdx.z;
    if (z < 3) {
        const float* in = z == 0 ? X0 : (z == 1 ? X1 : X2);
        bf16* out = z == 0 ? O0 : (z == 1 ? O1 : O2);
        int idx = blockIdx.x * blockDim.x + threadIdx.x;
        int stride = gridDim.x * blockDim.x;
        for (int i = idx; i < n4; i += stride) {
            float4 v = reinterpret_cast<const float4*>(in)[i];
            reinterpret_cast<uint2*>(out)[i] = make_uint2(pack2bf(v.x, v.y), pack2bf(v.z, v.w));
        }
    } else {
        const int w = z - 3;
        const float* W = w == 0 ? W0 : (w == 1 ? W1 : (w == 2 ? W2 : W3));
        bf16* WT = w == 0 ? T0 : (w == 1 ? T1 : (w == 2 ? T2 : T3));
        __shared__ float t[32][33];
        int bx = (blockIdx.x & 31) * 32, by = (blockIdx.x >> 5) * 32;
        int x = threadIdx.x & 31, y = threadIdx.x >> 5;
        #pragma unroll
        for (int i = 0; i < 4; ++i)
            t[y + 8*i][x] = W[(size_t)(by + y + 8*i) * 1024 + bx + x];
        __syncthreads();
        #pragma unroll
        for (int i = 0; i < 4; ++i)
            WT[(size_t)(bx + y + 8*i) * 1024 + by + x] = __float2bfloat16(t[x][y + 8*i]);
    }
}

// ---------------- GEMM: C[4096,NTOT] = A[4096,1024] @ BT^T + bias ----------------
// m97 structure: 128xNTILE tile, BK=64, single-buffered LDS, global_load_lds w16,
// XOR-swizzled rows via pre-swizzled global src, two barriers per K-step.
// mode = mode_base+z: 0 bf16 out *log2e/sqrt2 | 1 bf16 | 2 bf16 -> Vt[b][h][dv][s] | 3 fp32
template<int NTILE>
__global__ __launch_bounds__(256, 3)
void gemm_bt(const bf16* __restrict__ A0, const bf16* __restrict__ A1, const bf16* __restrict__ A2,
             const bf16* __restrict__ B0, const bf16* __restrict__ B1, const bf16* __restrict__ B2,
             const float* __restrict__ bi0, const float* __restrict__ bi1, const float* __restrict__ bi2,
             void* __restrict__ O0, void* __restrict__ O1, void* __restrict__ O2,
             int mode_base)
{
    const int f = blockIdx.x;
    int x, y, z;
    if (NTILE == 128) {
        const int s = f >> 3;
        y = s & 7;
        const int t = (f & 7) + 8 * (s >> 3);
        x = t & 31; z = t >> 5;
    } else {
        const int s = f >> 3;
        y = s & 15;
        x = (f & 7) + 8 * (s >> 4);
        z = 0;
    }
    const bf16* A  = z == 0 ? A0 : (z == 1 ? A1 : A2);
    const bf16* BT = z == 0 ? B0 : (z == 1 ? B1 : B2);
    const float* bias = z == 0 ? bi0 : (z == 1 ? bi1 : bi2);
    void* Cout = z == 0 ? O0 : (z == 1 ? O1 : O2);
    const int mode = mode_base + z;

    constexpr int MF = (NTILE == 128) ? 4 : 2;
    __shared__ __align__(16) char Abuf[16384];
    __shared__ __align__(16) char Bbuf[NTILE * 128];
    const int tid = threadIdx.x;
    const int wave = tid >> 6, lane = tid & 63;
    const int g = lane >> 4, ln = lane & 15;
    const int m0 = x * 128, n0 = y * NTILE;
    const int wm = (NTILE == 128) ? (wave >> 1) * 64 : wave * 32;
    const int wn = (NTILE == 128) ? (wave & 1) * 64 : 0;
    const int lnsw = (ln & 7) << 4;

    f32x4 acc[MF][4] = {};

    for (int k0 = 0; k0 < 1024; k0 += 64) {
        __syncthreads();
        #pragma unroll
        for (int rd = 0; rd < 4; ++rd) {
            int row = rd * 32 + (tid >> 3);
            int src = ((tid & 7) * 16) ^ (((tid >> 3) & 7) << 4);
            gload_lds16((const char*)(A + (size_t)(m0 + row) * 1024 + k0) + src,
                        Abuf + rd * 4096 + tid * 16);
        }
        #pragma unroll
        for (int rd = 0; rd < NTILE / 32; ++rd) {
            int row = rd * 32 + (tid >> 3);
            int src = ((tid & 7) * 16) ^ (((tid >> 3) & 7) << 4);
            gload_lds16((const char*)(BT + (size_t)(n0 + row) * 1024 + k0) + src,
                        Bbuf + rd * 4096 + tid * 16);
        }
        __syncthreads();
        #pragma unroll
        for (int kk = 0; kk < 2; ++kk) {
            bf16x8 af[MF], bfr[4];
            #pragma unroll
            for (int mf = 0; mf < MF; ++mf)
                af[mf] = *(const bf16x8*)&Abuf[(wm + mf*16 + ln) * 128 + ((kk*64 + g*16) ^ lnsw)];
            #pragma unroll
            for (int nf = 0; nf < 4; ++nf)
                bfr[nf] = *(const bf16x8*)&Bbuf[(wn + nf*16 + ln) * 128 + ((kk*64 + g*16) ^ lnsw)];
            #pragma unroll
            for (int mf = 0; mf < MF; ++mf)
                #pragma unroll
                for (int nf = 0; nf < 4; ++nf)
                    acc[mf][nf] = __builtin_amdgcn_mfma_f32_16x16x32_bf16(af[mf], bfr[nf], acc[mf][nf], 0, 0, 0);
        }
    }

    const float scl = (mode == 0) ? (0.70710678118654752f * 1.44269504088896340f) : 1.0f;
    #pragma unroll
    for (int mf = 0; mf < MF; ++mf) {
        #pragma unroll
        for (int nf = 0; nf < 4; ++nf) {
            int col = n0 + wn + nf*16 + ln;
            float bv = bias[col];
            #pragma unroll
            for (int r = 0; r < 4; ++r) {
                int row = m0 + wm + mf*16 + g*4 + r;
                float v = (acc[mf][nf][r] + bv) * scl;
                if (mode == 0 || mode == 1) {
                    ((bf16*)Cout)[(size_t)row * 1024 + col] = __float2bfloat16(v);
                } else if (mode == 2) {
                    int b = row >> 11, ss = row & 2047;
                    int hh = col >> 6, dv = col & 63;
                    ((bf16*)Cout)[(((size_t)(b*16 + hh) * 64 + dv) << 11) + ss] = __float2bfloat16(v);
                } else {
                    ((float*)Cout)[(size_t)row * 1024 + col] = v;
                }
            }
        }
    }
}

// ---------------- flash attention (r8 best config) ----------------
// qh: [B*S][1024] bf16 pre-scaled by log2e/sqrt(2); kh: [B*S][1024] bf16;
// vt: [B][H][64][2048] bf16; aout: [B*S][1024] bf16.
// 128 q/block, 4 waves x 32 q. KV staged 128 rows/iter (dbuf, 64KB LDS).
// Phase order per iter: QK_A,QK_B (MFMA) -> SM_A,SM_B (VALU/TRANS) -> PV_A,PV_B.
__global__ __launch_bounds__(256, 2)
void attn_kernel(const bf16* __restrict__ qh, const bf16* __restrict__ kh,
                 const bf16* __restrict__ vt, bf16* __restrict__ aout)
{
    __shared__ __align__(16) bf16 Kls[2][128 * 64];
    __shared__ __align__(16) bf16 Vls[2][64 * 128];
    const int f = blockIdx.x;
    const int xcd = f & 7, s = f >> 3, i = s & 15, ghi = s >> 4;
    const int bh = xcd + 8 * ghi;
    const int b = bh >> 4, h = bh & 15;
    const int q0 = i * 128;

    const int tid = threadIdx.x;
    const int wave = tid >> 6, lane = tid & 63;
    const int g = lane >> 4, ln = lane & 15;
    const int srow = lane >> 3;
    const int scol = ((lane & 7) * 16) ^ ((srow & 7) << 4);
    const int lnsw = (ln & 7) << 4;

    const bf16* kbase = kh + (size_t)(b * 2048) * 1024 + h * 64;
    const bf16* vbase = vt + (size_t)bh * 64 * 2048;

    const int vrow_in = lane >> 4;
    const int vcol16 = lane & 15;

    bf16x8 qf[2][2];
    #pragma unroll
    for (int nf = 0; nf < 2; ++nf) {
        const bf16* qrow = qh + (size_t)(b*2048 + q0 + wave*32 + nf*16 + ln) * 1024 + h*64;
        qf[nf][0] = *(const bf16x8*)(qrow + g*8);
        qf[nf][1] = *(const bf16x8*)(qrow + 32 + g*8);
    }

    auto stageKV = [&](int kv0, int buf) {
        #pragma unroll
        for (int c2 = 0; c2 < 4; ++c2) {
            int c = wave * 4 + c2;
            int krow = c * 8 + srow;
            gload_lds16((const char*)(kbase + (size_t)(kv0 + krow) * 1024) + scol,
                        (char*)&Kls[buf][0] + c * 1024);
        }
        #pragma unroll
        for (int c2 = 0; c2 < 4; ++c2) {
            int c = wave * 4 + c2;
            int vrow = c * 4 + vrow_in;
            int sc16 = vcol16 ^ (vrow & 15);
            gload_lds16((const char*)(vbase + (size_t)vrow * 2048 + kv0) + sc16 * 16,
                        (char*)&Vls[buf][0] + c * 1024);
        }
    };

    stageKV(0, 0);

    f32x4 oacc[4][2] = {};
    f32x4 lacc[2] = {};
    union PU { unsigned u[4]; bf16x8 v; };
    PU ones;
    ones.u[0] = ones.u[1] = ones.u[2] = ones.u[3] = 0x3F803F80u;  // bf16 1.0 x2

    for (int t = 0; t < 16; ++t) {
        const int cur = t & 1;
        if (t < 15) {
            stageKV((t + 1) * 128, cur ^ 1);
            asm volatile("s_waitcnt vmcnt(8)\n\ts_barrier" ::: "memory");
        } else {
            asm volatile("s_waitcnt vmcnt(0)\n\ts_barrier" ::: "memory");
        }
        __builtin_amdgcn_sched_barrier(0);

        const char* Kc = (const char*)&Kls[cur][0];
        const char* Vc = (const char*)&Vls[cur][0];

        // ---- QK for both halves (independent MFMA chains) ----
        f32x4 sacA[4][2] = {}, sacB[4][2] = {};
        __builtin_amdgcn_s_setprio(1);
        #pragma unroll
        for (int kk = 0; kk < 2; ++kk) {
            bf16x8 kf[4];
            #pragma unroll
            for (int mf = 0; mf < 4; ++mf)
                kf[mf] = *(const bf16x8*)(Kc + (mf*16 + ln) * 128 + ((kk*64 + g*16) ^ lnsw));
            #pragma unroll
            for (int mf = 0; mf < 4; ++mf)
                #pragma unroll
                for (int nf = 0; nf < 2; ++nf)
                    sacA[mf][nf] = __builtin_amdgcn_mfma_f32_16x16x32_bf16(kf[mf], qf[nf][kk], sacA[mf][nf], 0, 0, 0);
        }
        #pragma unroll
        for (int kk = 0; kk < 2; ++kk) {
            bf16x8 kf[4];
            #pragma unroll
            for (int mf = 0; mf < 4; ++mf)
                kf[mf] = *(const bf16x8*)(Kc + (64 + mf*16 + ln) * 128 + ((kk*64 + g*16) ^ lnsw));
            #pragma unroll
            for (int mf = 0; mf < 4; ++mf)
                #pragma unroll
                for (int nf = 0; nf < 2; ++nf)
                    sacB[mf][nf] = __builtin_amdgcn_mfma_f32_16x16x32_bf16(kf[mf], qf[nf][kk], sacB[mf][nf], 0, 0, 0);
        }
        __builtin_amdgcn_s_setprio(0);

        // ---- softmax for BOTH halves (VALU/TRANS) ----
        PU pfh[2][2][2];   // [ha][nf][kk]
        #pragma unroll
        for (int ha = 0; ha < 2; ++ha) {
            f32x4 (&sac)[4][2] = ha ? sacB : sacA;
            #pragma unroll
            for (int nf = 0; nf < 2; ++nf) {
                unsigned w[4][2];
                #pragma unroll
                for (int mf = 0; mf < 4; ++mf) {
                    float e0 = fexp2(sac[mf][nf][0]);
                    float e1 = fexp2(sac[mf][nf][1]);
                    float e2 = fexp2(sac[mf][nf][2]);
                    float e3 = fexp2(sac[mf][nf][3]);
                    w[mf][0] = cvtpk(e0, e1);
                    w[mf][1] = cvtpk(e2, e3);
                }
                #pragma unroll
                for (int kk = 0; kk < 2; ++kk) {
                    #pragma unroll
                    for (int rp = 0; rp < 2; ++rp) {
                        unsigned a = w[2*kk][rp], bb = w[2*kk + 1][rp];
                        pls32(a, bb);
                        pls16(a, bb);
                        pfh[ha][nf][kk].u[rp] = a;
                        pfh[ha][nf][kk].u[2 + rp] = bb;
                    }
                }
            }
        }

        // ---- PV for both halves ----
        __builtin_amdgcn_s_setprio(1);
        #pragma unroll
        for (int ha = 0; ha < 2; ++ha) {
            #pragma unroll
            for (int kk = 0; kk < 2; ++kk) {
                bf16x8 vf[4];
                #pragma unroll
                for (int mf = 0; mf < 4; ++mf)
                    vf[mf] = *(const bf16x8*)(Vc + (mf*16 + ln) * 256 + (((ha*8 + kk*4 + g) ^ ln) << 4));
                #pragma unroll
                for (int nf = 0; nf < 2; ++nf)
                    lacc[nf] = __builtin_amdgcn_mfma_f32_16x16x32_bf16(ones.v, pfh[ha][nf][kk].v, lacc[nf], 0, 0, 0);
                #pragma unroll
                for (int mf = 0; mf < 4; ++mf)
                    #pragma unroll
                    for (int nf = 0; nf < 2; ++nf)
                        oacc[mf][nf] = __builtin_amdgcn_mfma_f32_16x16x32_bf16(vf[mf], pfh[ha][nf][kk].v, oacc[mf][nf], 0, 0, 0);
            }
        }
        __builtin_amdgcn_s_setprio(0);
        __builtin_amdgcn_sched_barrier(0);
        asm volatile("s_barrier" ::: "memory");
    }

    #pragma unroll
    for (int nf = 0; nf < 2; ++nf) {
        float inv = 1.0f / lacc[nf][0];
        int q = q0 + wave*32 + nf*16 + ln;
        bf16* orow = aout + (size_t)(b*2048 + q) * 1024 + h * 64;
        #pragma unroll
        for (int mf = 0; mf < 4; ++mf) {
            *(uint2*)(orow + mf*16 + g*4) = make_uint2(
                pack2bf(oacc[mf][nf][0] * inv, oacc[mf][nf][1] * inv),
                pack2bf(oacc[mf][nf][2] * inv, oacc[mf][nf][3] * inv));
        }
    }
}

// ---------------- host ----------------
extern "C" void kernel_launch(void* const* d_in, const int* in_sizes, int n_in,
                              void* d_out, int out_size, void* d_ws, size_t ws_size,
                              hipStream_t stream)
{
    const float* Q  = (const float*)d_in[0];
    const float* K  = (const float*)d_in[1];
    const float* V  = (const float*)d_in[2];
    const float* Wq = (const float*)d_in[3];
    const float* bq = (const float*)d_in[4];
    const float* Wk = (const float*)d_in[5];
    const float* bk = (const float*)d_in[6];
    const float* Wv = (const float*)d_in[7];
    const float* bv = (const float*)d_in[8];
    const float* Wo = (const float*)d_in[9];
    const float* bo = (const float*)d_in[10];

    char* ws = (char*)d_ws;
    const size_t MB = 1024 * 1024;
    bf16* Qbf  = (bf16*)(ws + 0);
    bf16* Kbf  = (bf16*)(ws + 8*MB);
    bf16* Vbf  = (bf16*)(ws + 16*MB);
    bf16* WqT  = (bf16*)(ws + 24*MB);
    bf16* WkT  = (bf16*)(ws + 26*MB);
    bf16* WvT  = (bf16*)(ws + 28*MB);
    bf16* WoT  = (bf16*)(ws + 30*MB);
    bf16* qhp  = (bf16*)(ws + 32*MB);
    bf16* khp  = (bf16*)(ws + 40*MB);
    bf16* vtp  = (bf16*)(ws + 48*MB);
    bf16* aout = (bf16*)(ws + 0);      // alias Qbf (dead after projections)

    const int n4 = (2 * 2048 * 1024) / 4;
    prep_kernel<<<dim3(1024, 1, 7), 256, 0, stream>>>(Q, K, V, Qbf, Kbf, Vbf,
                                                      Wq, Wk, Wv, Wo, WqT, WkT, WvT, WoT, n4);

    gemm_bt<128><<<768, 256, 0, stream>>>(Qbf, Kbf, Vbf, WqT, WkT, WvT,
                                          bq, bk, bv, qhp, khp, vtp, 0);

    attn_kernel<<<512, 256, 0, stream>>>(qhp, khp, vtp, aout);

    gemm_bt<64><<<512, 256, 0, stream>>>(aout, aout, aout, WoT, WoT, WoT,
                                         bo, bo, bo, d_out, d_out, d_out, 3);
}

// Round 15
// 105.957 us; speedup vs baseline: 1.1019x; 1.0598x over previous
//
#include <hip/hip_runtime.h>
#include <hip/hip_bf16.h>

// MHA layer B=2, S=2048, DM=1024, H=16, DK=DV=64 on gfx950.
// prep (conv fp32->bf16 + weight transpose, 1 launch) -> 3 proj GEMMs
// (m97 structure, vectorized epilogue via LDS roundtrip / packed stores) ->
// flash attention (r8 best) -> out GEMM (128x64, chunked LDS epilogue).

using bf16 = __hip_bfloat16;
typedef __attribute__((ext_vector_type(4))) float f32x4;
typedef __attribute__((ext_vector_type(8))) short bf16x8;

__device__ __forceinline__ void gload_lds16(const void* gsrc, void* ldst) {
    __builtin_amdgcn_global_load_lds(
        (const __attribute__((address_space(1))) void*)gsrc,
        (__attribute__((address_space(3))) void*)ldst,
        16, 0, 0);
}

__device__ __forceinline__ float fexp2(float x) {
    float r; asm("v_exp_f32 %0, %1" : "=v"(r) : "v"(x)); return r;
}

__device__ __forceinline__ unsigned cvtpk(float a, float b) {
    unsigned d; asm("v_cvt_pk_bf16_f32 %0, %1, %2" : "=v"(d) : "v"(a), "v"(b));
    return d;
}

__device__ __forceinline__ void pls32(unsigned &a, unsigned &b) {
    asm("v_permlane32_swap_b32 %0, %1" : "+v"(a), "+v"(b));
}
__device__ __forceinline__ void pls16(unsigned &a, unsigned &b) {
    asm("v_permlane16_swap_b32 %0, %1" : "+v"(a), "+v"(b));
}

__device__ __forceinline__ unsigned pack2bf(float a, float b) {
    unsigned short ua = __builtin_bit_cast(unsigned short, __float2bfloat16(a));
    unsigned short ub = __builtin_bit_cast(unsigned short, __float2bfloat16(b));
    return (unsigned)ua | ((unsigned)ub << 16);
}

// ---------------- prep: z=0..2 conv fp32->bf16 (grid-stride), z=3..6 transpose ----------------
__global__ void prep_kernel(const float* __restrict__ X0, const float* __restrict__ X1,
                            const float* __restrict__ X2,
                            bf16* __restrict__ O0, bf16* __restrict__ O1, bf16* __restrict__ O2,
                            const float* __restrict__ W0, const float* __restrict__ W1,
                            const float* __restrict__ W2, const float* __restrict__ W3,
                            bf16* __restrict__ T0, bf16* __restrict__ T1,
                            bf16* __restrict__ T2, bf16* __restrict__ T3,
                            int n4) {
    const int z = blockIdx.z;
    if (z < 3) {
        const float* in = z == 0 ? X0 : (z == 1 ? X1 : X2);
        bf16* out = z == 0 ? O0 : (z == 1 ? O1 : O2);
        int idx = blockIdx.x * blockDim.x + threadIdx.x;
        int stride = gridDim.x * blockDim.x;
        for (int i = idx; i < n4; i += stride) {
            float4 v = reinterpret_cast<const float4*>(in)[i];
            reinterpret_cast<uint2*>(out)[i] = make_uint2(pack2bf(v.x, v.y), pack2bf(v.z, v.w));
        }
    } else {
        const int w = z - 3;
        const float* W = w == 0 ? W0 : (w == 1 ? W1 : (w == 2 ? W2 : W3));
        bf16* WT = w == 0 ? T0 : (w == 1 ? T1 : (w == 2 ? T2 : T3));
        __shared__ float t[32][33];
        int bx = (blockIdx.x & 31) * 32, by = (blockIdx.x >> 5) * 32;
        int x = threadIdx.x & 31, y = threadIdx.x >> 5;
        #pragma unroll
        for (int i = 0; i < 4; ++i)
            t[y + 8*i][x] = W[(size_t)(by + y + 8*i) * 1024 + bx + x];
        __syncthreads();
        #pragma unroll
        for (int i = 0; i < 4; ++i)
            WT[(size_t)(bx + y + 8*i) * 1024 + by + x] = __float2bfloat16(t[x][y + 8*i]);
    }
}

// ---------------- GEMM: C[4096,NTOT] = A[4096,1024] @ BT^T + bias ----------------
// m97 structure: 128xNTILE tile, BK=64, single-buffered LDS, global_load_lds w16,
// XOR-swizzled rows via pre-swizzled global src, two barriers per K-step.
// Epilogues: mode 0/1 bf16 via LDS-roundtrip coalesced uint4 stores; mode 2
// (Vt[b][h][dv][s]) packed uint2 (4 consecutive s); mode 3 fp32 via 2-chunk LDS.
template<int NTILE>
__global__ __launch_bounds__(256, 3)
void gemm_bt(const bf16* __restrict__ A0, const bf16* __restrict__ A1, const bf16* __restrict__ A2,
             const bf16* __restrict__ B0, const bf16* __restrict__ B1, const bf16* __restrict__ B2,
             const float* __restrict__ bi0, const float* __restrict__ bi1, const float* __restrict__ bi2,
             void* __restrict__ O0, void* __restrict__ O1, void* __restrict__ O2,
             int mode_base)
{
    const int f = blockIdx.x;
    int x, y, z;
    if (NTILE == 128) {
        const int s = f >> 3;
        y = s & 7;
        const int t = (f & 7) + 8 * (s >> 3);
        x = t & 31; z = t >> 5;
    } else {
        const int s = f >> 3;
        y = s & 15;
        x = (f & 7) + 8 * (s >> 4);
        z = 0;
    }
    const bf16* A  = z == 0 ? A0 : (z == 1 ? A1 : A2);
    const bf16* BT = z == 0 ? B0 : (z == 1 ? B1 : B2);
    const float* bias = z == 0 ? bi0 : (z == 1 ? bi1 : bi2);
    void* Cout = z == 0 ? O0 : (z == 1 ? O1 : O2);
    const int mode = mode_base + z;

    __shared__ __align__(16) char Sbuf[16384 + NTILE * 128];
    char* Abuf = Sbuf;
    char* Bbuf = Sbuf + 16384;
    constexpr int MF = (NTILE == 128) ? 4 : 2;
    const int tid = threadIdx.x;
    const int wave = tid >> 6, lane = tid & 63;
    const int g = lane >> 4, ln = lane & 15;
    const int m0 = x * 128, n0 = y * NTILE;
    const int wm = (NTILE == 128) ? (wave >> 1) * 64 : wave * 32;
    const int wn = (NTILE == 128) ? (wave & 1) * 64 : 0;
    const int lnsw = (ln & 7) << 4;

    f32x4 acc[MF][4] = {};

    for (int k0 = 0; k0 < 1024; k0 += 64) {
        __syncthreads();
        #pragma unroll
        for (int rd = 0; rd < 4; ++rd) {
            int row = rd * 32 + (tid >> 3);
            int src = ((tid & 7) * 16) ^ (((tid >> 3) & 7) << 4);
            gload_lds16((const char*)(A + (size_t)(m0 + row) * 1024 + k0) + src,
                        Abuf + rd * 4096 + tid * 16);
        }
        #pragma unroll
        for (int rd = 0; rd < NTILE / 32; ++rd) {
            int row = rd * 32 + (tid >> 3);
            int src = ((tid & 7) * 16) ^ (((tid >> 3) & 7) << 4);
            gload_lds16((const char*)(BT + (size_t)(n0 + row) * 1024 + k0) + src,
                        Bbuf + rd * 4096 + tid * 16);
        }
        __syncthreads();
        #pragma unroll
        for (int kk = 0; kk < 2; ++kk) {
            bf16x8 af[MF], bfr[4];
            #pragma unroll
            for (int mf = 0; mf < MF; ++mf)
                af[mf] = *(const bf16x8*)&Abuf[(wm + mf*16 + ln) * 128 + ((kk*64 + g*16) ^ lnsw)];
            #pragma unroll
            for (int nf = 0; nf < 4; ++nf)
                bfr[nf] = *(const bf16x8*)&Bbuf[(wn + nf*16 + ln) * 128 + ((kk*64 + g*16) ^ lnsw)];
            #pragma unroll
            for (int mf = 0; mf < MF; ++mf)
                #pragma unroll
                for (int nf = 0; nf < 4; ++nf)
                    acc[mf][nf] = __builtin_amdgcn_mfma_f32_16x16x32_bf16(af[mf], bfr[nf], acc[mf][nf], 0, 0, 0);
        }
    }

    const float scl = (mode == 0) ? (0.70710678118654752f * 1.44269504088896340f) : 1.0f;

    if (mode == 2) {
        // Vt[b][h][dv][s]: fragment's 4 values are 4 consecutive s at fixed dv -> uint2
        #pragma unroll
        for (int mf = 0; mf < MF; ++mf) {
            #pragma unroll
            for (int nf = 0; nf < 4; ++nf) {
                int col = n0 + wn + nf*16 + ln;
                float bv = bias[col];
                int row0 = m0 + wm + mf*16 + g*4;
                int b = row0 >> 11, ss = row0 & 2047;
                int hh = col >> 6, dv = col & 63;
                bf16* dst = (bf16*)Cout + (((size_t)(b*16 + hh) * 64 + dv) << 11) + ss;
                *(uint2*)dst = make_uint2(
                    pack2bf(acc[mf][nf][0] + bv, acc[mf][nf][1] + bv),
                    pack2bf(acc[mf][nf][2] + bv, acc[mf][nf][3] + bv));
            }
        }
    } else if (mode == 0 || mode == 1) {
        // LDS roundtrip: tile [128 rows][NTILE cols] bf16 at row*(NTILE*2) bytes
        __syncthreads();
        #pragma unroll
        for (int mf = 0; mf < MF; ++mf) {
            #pragma unroll
            for (int nf = 0; nf < 4; ++nf) {
                int tcol = wn + nf*16 + ln;
                float bv = bias[n0 + tcol];
                #pragma unroll
                for (int r = 0; r < 4; ++r) {
                    int trow = wm + mf*16 + g*4 + r;
                    *(unsigned short*)(Sbuf + trow * (NTILE*2) + tcol * 2) =
                        __builtin_bit_cast(unsigned short,
                            __float2bfloat16((acc[mf][nf][r] + bv) * scl));
                }
            }
        }
        __syncthreads();
        // coalesced: NTILE/8 threads cover one row's 16B chunks
        constexpr int TPR = NTILE / 8;           // threads per row
        const int rr = tid / TPR, cc = (tid % TPR) * 8;
        #pragma unroll
        for (int it = 0; it < 128 / (256 / TPR); ++it) {
            int row = it * (256 / TPR) + rr;
            uint4 v = *(const uint4*)(Sbuf + row * (NTILE*2) + cc * 2);
            *(uint4*)((bf16*)Cout + (size_t)(m0 + row) * 1024 + n0 + cc) = v;
        }
    } else {
        // mode 3: fp32 out via 2 chunks of 32 cols (16KB each) through Sbuf
        #pragma unroll
        for (int p = 0; p < 2; ++p) {
            __syncthreads();
            #pragma unroll
            for (int mf = 0; mf < MF; ++mf) {
                #pragma unroll
                for (int j = 0; j < 2; ++j) {
                    int nf = p * 2 + j;
                    int tcol = j*16 + ln;            // 0..31 within chunk
                    float bv = bias[n0 + wn + nf*16 + ln];
                    #pragma unroll
                    for (int r = 0; r < 4; ++r) {
                        int trow = wm + mf*16 + g*4 + r;
                        *(float*)(Sbuf + trow * 128 + tcol * 4) = acc[mf][nf][r] + bv;
                    }
                }
            }
            __syncthreads();
            // 8 threads x 16B = 128B per row; 32 rows per iter
            const int rr = tid >> 3, cc = (tid & 7) * 4;
            #pragma unroll
            for (int it = 0; it < 4; ++it) {
                int row = it * 32 + rr;
                uint4 v = *(const uint4*)(Sbuf + row * 128 + cc * 4);
                *(uint4*)((float*)Cout + (size_t)(m0 + row) * 1024 + n0 + p*32 + cc) = v;
            }
        }
    }
}

// ---------------- flash attention (r8 best config) ----------------
// qh: [B*S][1024] bf16 pre-scaled by log2e/sqrt(2); kh: [B*S][1024] bf16;
// vt: [B][H][64][2048] bf16; aout: [B*S][1024] bf16.
// 128 q/block, 4 waves x 32 q. KV staged 128 rows/iter (dbuf, 64KB LDS).
// Phase order per iter: QK_A,QK_B (MFMA) -> SM_A,SM_B (VALU/TRANS) -> PV_A,PV_B.
__global__ __launch_bounds__(256, 2)
void attn_kernel(const bf16* __restrict__ qh, const bf16* __restrict__ kh,
                 const bf16* __restrict__ vt, bf16* __restrict__ aout)
{
    __shared__ __align__(16) bf16 Kls[2][128 * 64];
    __shared__ __align__(16) bf16 Vls[2][64 * 128];
    const int f = blockIdx.x;
    const int xcd = f & 7, s = f >> 3, i = s & 15, ghi = s >> 4;
    const int bh = xcd + 8 * ghi;
    const int b = bh >> 4, h = bh & 15;
    const int q0 = i * 128;

    const int tid = threadIdx.x;
    const int wave = tid >> 6, lane = tid & 63;
    const int g = lane >> 4, ln = lane & 15;
    const int srow = lane >> 3;
    const int scol = ((lane & 7) * 16) ^ ((srow & 7) << 4);
    const int lnsw = (ln & 7) << 4;

    const bf16* kbase = kh + (size_t)(b * 2048) * 1024 + h * 64;
    const bf16* vbase = vt + (size_t)bh * 64 * 2048;

    const int vrow_in = lane >> 4;
    const int vcol16 = lane & 15;

    bf16x8 qf[2][2];
    #pragma unroll
    for (int nf = 0; nf < 2; ++nf) {
        const bf16* qrow = qh + (size_t)(b*2048 + q0 + wave*32 + nf*16 + ln) * 1024 + h*64;
        qf[nf][0] = *(const bf16x8*)(qrow + g*8);
        qf[nf][1] = *(const bf16x8*)(qrow + 32 + g*8);
    }

    auto stageKV = [&](int kv0, int buf) {
        #pragma unroll
        for (int c2 = 0; c2 < 4; ++c2) {
            int c = wave * 4 + c2;
            int krow = c * 8 + srow;
            gload_lds16((const char*)(kbase + (size_t)(kv0 + krow) * 1024) + scol,
                        (char*)&Kls[buf][0] + c * 1024);
        }
        #pragma unroll
        for (int c2 = 0; c2 < 4; ++c2) {
            int c = wave * 4 + c2;
            int vrow = c * 4 + vrow_in;
            int sc16 = vcol16 ^ (vrow & 15);
            gload_lds16((const char*)(vbase + (size_t)vrow * 2048 + kv0) + sc16 * 16,
                        (char*)&Vls[buf][0] + c * 1024);
        }
    };

    stageKV(0, 0);

    f32x4 oacc[4][2] = {};
    f32x4 lacc[2] = {};
    union PU { unsigned u[4]; bf16x8 v; };
    PU ones;
    ones.u[0] = ones.u[1] = ones.u[2] = ones.u[3] = 0x3F803F80u;  // bf16 1.0 x2

    for (int t = 0; t < 16; ++t) {
        const int cur = t & 1;
        if (t < 15) {
            stageKV((t + 1) * 128, cur ^ 1);
            asm volatile("s_waitcnt vmcnt(8)\n\ts_barrier" ::: "memory");
        } else {
            asm volatile("s_waitcnt vmcnt(0)\n\ts_barrier" ::: "memory");
        }
        __builtin_amdgcn_sched_barrier(0);

        const char* Kc = (const char*)&Kls[cur][0];
        const char* Vc = (const char*)&Vls[cur][0];

        // ---- QK for both halves (independent MFMA chains) ----
        f32x4 sacA[4][2] = {}, sacB[4][2] = {};
        __builtin_amdgcn_s_setprio(1);
        #pragma unroll
        for (int kk = 0; kk < 2; ++kk) {
            bf16x8 kf[4];
            #pragma unroll
            for (int mf = 0; mf < 4; ++mf)
                kf[mf] = *(const bf16x8*)(Kc + (mf*16 + ln) * 128 + ((kk*64 + g*16) ^ lnsw));
            #pragma unroll
            for (int mf = 0; mf < 4; ++mf)
                #pragma unroll
                for (int nf = 0; nf < 2; ++nf)
                    sacA[mf][nf] = __builtin_amdgcn_mfma_f32_16x16x32_bf16(kf[mf], qf[nf][kk], sacA[mf][nf], 0, 0, 0);
        }
        #pragma unroll
        for (int kk = 0; kk < 2; ++kk) {
            bf16x8 kf[4];
            #pragma unroll
            for (int mf = 0; mf < 4; ++mf)
                kf[mf] = *(const bf16x8*)(Kc + (64 + mf*16 + ln) * 128 + ((kk*64 + g*16) ^ lnsw));
            #pragma unroll
            for (int mf = 0; mf < 4; ++mf)
                #pragma unroll
                for (int nf = 0; nf < 2; ++nf)
                    sacB[mf][nf] = __builtin_amdgcn_mfma_f32_16x16x32_bf16(kf[mf], qf[nf][kk], sacB[mf][nf], 0, 0, 0);
        }
        __builtin_amdgcn_s_setprio(0);

        // ---- softmax for BOTH halves (VALU/TRANS) ----
        PU pfh[2][2][2];   // [ha][nf][kk]
        #pragma unroll
        for (int ha = 0; ha < 2; ++ha) {
            f32x4 (&sac)[4][2] = ha ? sacB : sacA;
            #pragma unroll
            for (int nf = 0; nf < 2; ++nf) {
                unsigned w[4][2];
                #pragma unroll
                for (int mf = 0; mf < 4; ++mf) {
                    float e0 = fexp2(sac[mf][nf][0]);
                    float e1 = fexp2(sac[mf][nf][1]);
                    float e2 = fexp2(sac[mf][nf][2]);
                    float e3 = fexp2(sac[mf][nf][3]);
                    w[mf][0] = cvtpk(e0, e1);
                    w[mf][1] = cvtpk(e2, e3);
                }
                #pragma unroll
                for (int kk = 0; kk < 2; ++kk) {
                    #pragma unroll
                    for (int rp = 0; rp < 2; ++rp) {
                        unsigned a = w[2*kk][rp], bb = w[2*kk + 1][rp];
                        pls32(a, bb);
                        pls16(a, bb);
                        pfh[ha][nf][kk].u[rp] = a;
                        pfh[ha][nf][kk].u[2 + rp] = bb;
                    }
                }
            }
        }

        // ---- PV for both halves ----
        __builtin_amdgcn_s_setprio(1);
        #pragma unroll
        for (int ha = 0; ha < 2; ++ha) {
            #pragma unroll
            for (int kk = 0; kk < 2; ++kk) {
                bf16x8 vf[4];
                #pragma unroll
                for (int mf = 0; mf < 4; ++mf)
                    vf[mf] = *(const bf16x8*)(Vc + (mf*16 + ln) * 256 + (((ha*8 + kk*4 + g) ^ ln) << 4));
                #pragma unroll
                for (int nf = 0; nf < 2; ++nf)
                    lacc[nf] = __builtin_amdgcn_mfma_f32_16x16x32_bf16(ones.v, pfh[ha][nf][kk].v, lacc[nf], 0, 0, 0);
                #pragma unroll
                for (int mf = 0; mf < 4; ++mf)
                    #pragma unroll
                    for (int nf = 0; nf < 2; ++nf)
                        oacc[mf][nf] = __builtin_amdgcn_mfma_f32_16x16x32_bf16(vf[mf], pfh[ha][nf][kk].v, oacc[mf][nf], 0, 0, 0);
            }
        }
        __builtin_amdgcn_s_setprio(0);
        __builtin_amdgcn_sched_barrier(0);
        asm volatile("s_barrier" ::: "memory");
    }

    #pragma unroll
    for (int nf = 0; nf < 2; ++nf) {
        float inv = 1.0f / lacc[nf][0];
        int q = q0 + wave*32 + nf*16 + ln;
        bf16* orow = aout + (size_t)(b*2048 + q) * 1024 + h * 64;
        #pragma unroll
        for (int mf = 0; mf < 4; ++mf) {
            *(uint2*)(orow + mf*16 + g*4) = make_uint2(
                pack2bf(oacc[mf][nf][0] * inv, oacc[mf][nf][1] * inv),
                pack2bf(oacc[mf][nf][2] * inv, oacc[mf][nf][3] * inv));
        }
    }
}

// ---------------- host ----------------
extern "C" void kernel_launch(void* const* d_in, const int* in_sizes, int n_in,
                              void* d_out, int out_size, void* d_ws, size_t ws_size,
                              hipStream_t stream)
{
    const float* Q  = (const float*)d_in[0];
    const float* K  = (const float*)d_in[1];
    const float* V  = (const float*)d_in[2];
    const float* Wq = (const float*)d_in[3];
    const float* bq = (const float*)d_in[4];
    const float* Wk = (const float*)d_in[5];
    const float* bk = (const float*)d_in[6];
    const float* Wv = (const float*)d_in[7];
    const float* bv = (const float*)d_in[8];
    const float* Wo = (const float*)d_in[9];
    const float* bo = (const float*)d_in[10];

    char* ws = (char*)d_ws;
    const size_t MB = 1024 * 1024;
    bf16* Qbf  = (bf16*)(ws + 0);
    bf16* Kbf  = (bf16*)(ws + 8*MB);
    bf16* Vbf  = (bf16*)(ws + 16*MB);
    bf16* WqT  = (bf16*)(ws + 24*MB);
    bf16* WkT  = (bf16*)(ws + 26*MB);
    bf16* WvT  = (bf16*)(ws + 28*MB);
    bf16* WoT  = (bf16*)(ws + 30*MB);
    bf16* qhp  = (bf16*)(ws + 32*MB);
    bf16* khp  = (bf16*)(ws + 40*MB);
    bf16* vtp  = (bf16*)(ws + 48*MB);
    bf16* aout = (bf16*)(ws + 0);      // alias Qbf (dead after projections)

    const int n4 = (2 * 2048 * 1024) / 4;
    prep_kernel<<<dim3(1024, 1, 7), 256, 0, stream>>>(Q, K, V, Qbf, Kbf, Vbf,
                                                      Wq, Wk, Wv, Wo, WqT, WkT, WvT, WoT, n4);

    gemm_bt<128><<<768, 256, 0, stream>>>(Qbf, Kbf, Vbf, WqT, WkT, WvT,
                                          bq, bk, bv, qhp, khp, vtp, 0);

    attn_kernel<<<512, 256, 0, stream>>>(qhp, khp, vtp, aout);

    gemm_bt<64><<<512, 256, 0, stream>>>(aout, aout, aout, WoT, WoT, WoT,
                                         bo, bo, bo, d_out, d_out, d_out, 3);
}

// Round 16
// 105.048 us; speedup vs baseline: 1.1114x; 1.0087x over previous
//
#include <hip/hip_runtime.h>
#include <hip/hip_bf16.h>

// MHA layer B=2, S=2048, DM=1024, H=16, DK=DV=64 on gfx950.
// prep (conv fp32->bf16 + weight transpose, 1 launch) -> 3 proj GEMMs
// (m97 structure + counted-vmcnt double-buffer, vectorized epilogues) ->
// flash attention (r8 best) -> out GEMM (128x64, dbuf, chunked LDS epilogue).

using bf16 = __hip_bfloat16;
typedef __attribute__((ext_vector_type(4))) float f32x4;
typedef __attribute__((ext_vector_type(8))) short bf16x8;

__device__ __forceinline__ void gload_lds16(const void* gsrc, void* ldst) {
    __builtin_amdgcn_global_load_lds(
        (const __attribute__((address_space(1))) void*)gsrc,
        (__attribute__((address_space(3))) void*)ldst,
        16, 0, 0);
}

__device__ __forceinline__ float fexp2(float x) {
    float r; asm("v_exp_f32 %0, %1" : "=v"(r) : "v"(x)); return r;
}

__device__ __forceinline__ unsigned cvtpk(float a, float b) {
    unsigned d; asm("v_cvt_pk_bf16_f32 %0, %1, %2" : "=v"(d) : "v"(a), "v"(b));
    return d;
}

__device__ __forceinline__ void pls32(unsigned &a, unsigned &b) {
    asm("v_permlane32_swap_b32 %0, %1" : "+v"(a), "+v"(b));
}
__device__ __forceinline__ void pls16(unsigned &a, unsigned &b) {
    asm("v_permlane16_swap_b32 %0, %1" : "+v"(a), "+v"(b));
}

__device__ __forceinline__ unsigned pack2bf(float a, float b) {
    unsigned short ua = __builtin_bit_cast(unsigned short, __float2bfloat16(a));
    unsigned short ub = __builtin_bit_cast(unsigned short, __float2bfloat16(b));
    return (unsigned)ua | ((unsigned)ub << 16);
}

// ---------------- prep: z=0..2 conv fp32->bf16 (grid-stride), z=3..6 transpose ----------------
__global__ void prep_kernel(const float* __restrict__ X0, const float* __restrict__ X1,
                            const float* __restrict__ X2,
                            bf16* __restrict__ O0, bf16* __restrict__ O1, bf16* __restrict__ O2,
                            const float* __restrict__ W0, const float* __restrict__ W1,
                            const float* __restrict__ W2, const float* __restrict__ W3,
                            bf16* __restrict__ T0, bf16* __restrict__ T1,
                            bf16* __restrict__ T2, bf16* __restrict__ T3,
                            int n4) {
    const int z = blockIdx.z;
    if (z < 3) {
        const float* in = z == 0 ? X0 : (z == 1 ? X1 : X2);
        bf16* out = z == 0 ? O0 : (z == 1 ? O1 : O2);
        int idx = blockIdx.x * blockDim.x + threadIdx.x;
        int stride = gridDim.x * blockDim.x;
        for (int i = idx; i < n4; i += stride) {
            float4 v = reinterpret_cast<const float4*>(in)[i];
            reinterpret_cast<uint2*>(out)[i] = make_uint2(pack2bf(v.x, v.y), pack2bf(v.z, v.w));
        }
    } else {
        const int w = z - 3;
        const float* W = w == 0 ? W0 : (w == 1 ? W1 : (w == 2 ? W2 : W3));
        bf16* WT = w == 0 ? T0 : (w == 1 ? T1 : (w == 2 ? T2 : T3));
        __shared__ float t[32][33];
        int bx = (blockIdx.x & 31) * 32, by = (blockIdx.x >> 5) * 32;
        int x = threadIdx.x & 31, y = threadIdx.x >> 5;
        #pragma unroll
        for (int i = 0; i < 4; ++i)
            t[y + 8*i][x] = W[(size_t)(by + y + 8*i) * 1024 + bx + x];
        __syncthreads();
        #pragma unroll
        for (int i = 0; i < 4; ++i)
            WT[(size_t)(bx + y + 8*i) * 1024 + by + x] = __float2bfloat16(t[x][y + 8*i]);
    }
}

// ---------------- GEMM: C[4096,NTOT] = A[4096,1024] @ BT^T + bias ----------------
// m97 structure + counted-vmcnt DOUBLE-BUFFER: stage(k+1) issued before barrier,
// vmcnt(N) keeps the prefetch in flight across it (attn-proven pattern).
// Epilogues: mode 0/1 bf16 via LDS-roundtrip coalesced uint4 stores; mode 2
// (Vt[b][h][dv][s]) packed uint2; mode 3 fp32 via 2-chunk LDS.
template<int NTILE>
__global__ __launch_bounds__(256, (NTILE == 128) ? 2 : 3)
void gemm_bt(const bf16* __restrict__ A0, const bf16* __restrict__ A1, const bf16* __restrict__ A2,
             const bf16* __restrict__ B0, const bf16* __restrict__ B1, const bf16* __restrict__ B2,
             const float* __restrict__ bi0, const float* __restrict__ bi1, const float* __restrict__ bi2,
             void* __restrict__ O0, void* __restrict__ O1, void* __restrict__ O2,
             int mode_base)
{
    const int f = blockIdx.x;
    int x, y, z;
    if (NTILE == 128) {
        const int s = f >> 3;
        y = s & 7;
        const int t = (f & 7) + 8 * (s >> 3);
        x = t & 31; z = t >> 5;
    } else {
        const int s = f >> 3;
        y = s & 15;
        x = (f & 7) + 8 * (s >> 4);
        z = 0;
    }
    const bf16* A  = z == 0 ? A0 : (z == 1 ? A1 : A2);
    const bf16* BT = z == 0 ? B0 : (z == 1 ? B1 : B2);
    const float* bias = z == 0 ? bi0 : (z == 1 ? bi1 : bi2);
    void* Cout = z == 0 ? O0 : (z == 1 ? O1 : O2);
    const int mode = mode_base + z;

    constexpr int ABYTES = 16384;
    constexpr int BBYTES = NTILE * 128;
    constexpr int BUFB   = ABYTES + BBYTES;
    __shared__ __align__(16) char Sbuf[2 * BUFB];
    constexpr int MF = (NTILE == 128) ? 4 : 2;
    const int tid = threadIdx.x;
    const int wave = tid >> 6, lane = tid & 63;
    const int g = lane >> 4, ln = lane & 15;
    const int m0 = x * 128, n0 = y * NTILE;
    const int wm = (NTILE == 128) ? (wave >> 1) * 64 : wave * 32;
    const int wn = (NTILE == 128) ? (wave & 1) * 64 : 0;
    const int lnsw = (ln & 7) << 4;

    auto stage = [&](int k0, int buf) {
        char* Ab = Sbuf + buf * BUFB;
        char* Bb = Ab + ABYTES;
        #pragma unroll
        for (int rd = 0; rd < 4; ++rd) {
            int row = rd * 32 + (tid >> 3);
            int src = ((tid & 7) * 16) ^ (((tid >> 3) & 7) << 4);
            gload_lds16((const char*)(A + (size_t)(m0 + row) * 1024 + k0) + src,
                        Ab + rd * 4096 + tid * 16);
        }
        #pragma unroll
        for (int rd = 0; rd < NTILE / 32; ++rd) {
            int row = rd * 32 + (tid >> 3);
            int src = ((tid & 7) * 16) ^ (((tid >> 3) & 7) << 4);
            gload_lds16((const char*)(BT + (size_t)(n0 + row) * 1024 + k0) + src,
                        Bb + rd * 4096 + tid * 16);
        }
    };

    f32x4 acc[MF][4] = {};
    stage(0, 0);

    for (int k = 0; k < 16; ++k) {
        const int cur = k & 1;
        if (k < 15) {
            stage((k + 1) * 64, cur ^ 1);
            // wait current tile only; prefetch (4 + NTILE/32*... = per-thread loads of
            // next tile) stays in flight across the barrier.
            if (NTILE == 128) asm volatile("s_waitcnt vmcnt(8)\n\ts_barrier" ::: "memory");
            else              asm volatile("s_waitcnt vmcnt(6)\n\ts_barrier" ::: "memory");
        } else {
            asm volatile("s_waitcnt vmcnt(0)\n\ts_barrier" ::: "memory");
        }
        __builtin_amdgcn_sched_barrier(0);

        const char* Ab = Sbuf + cur * BUFB;
        const char* Bb = Ab + ABYTES;
        #pragma unroll
        for (int kk = 0; kk < 2; ++kk) {
            bf16x8 af[MF], bfr[4];
            #pragma unroll
            for (int mf = 0; mf < MF; ++mf)
                af[mf] = *(const bf16x8*)(Ab + (wm + mf*16 + ln) * 128 + ((kk*64 + g*16) ^ lnsw));
            #pragma unroll
            for (int nf = 0; nf < 4; ++nf)
                bfr[nf] = *(const bf16x8*)(Bb + (wn + nf*16 + ln) * 128 + ((kk*64 + g*16) ^ lnsw));
            #pragma unroll
            for (int mf = 0; mf < MF; ++mf)
                #pragma unroll
                for (int nf = 0; nf < 4; ++nf)
                    acc[mf][nf] = __builtin_amdgcn_mfma_f32_16x16x32_bf16(af[mf], bfr[nf], acc[mf][nf], 0, 0, 0);
        }
        __builtin_amdgcn_sched_barrier(0);
        asm volatile("s_barrier" ::: "memory");   // reads done (MFMAs consumed them)
    }

    const float scl = (mode == 0) ? (0.70710678118654752f * 1.44269504088896340f) : 1.0f;

    if (mode == 2) {
        // Vt[b][h][dv][s]: fragment's 4 values are 4 consecutive s at fixed dv -> uint2
        #pragma unroll
        for (int mf = 0; mf < MF; ++mf) {
            #pragma unroll
            for (int nf = 0; nf < 4; ++nf) {
                int col = n0 + wn + nf*16 + ln;
                float bv = bias[col];
                int row0 = m0 + wm + mf*16 + g*4;
                int b = row0 >> 11, ss = row0 & 2047;
                int hh = col >> 6, dv = col & 63;
                bf16* dst = (bf16*)Cout + (((size_t)(b*16 + hh) * 64 + dv) << 11) + ss;
                *(uint2*)dst = make_uint2(
                    pack2bf(acc[mf][nf][0] + bv, acc[mf][nf][1] + bv),
                    pack2bf(acc[mf][nf][2] + bv, acc[mf][nf][3] + bv));
            }
        }
    } else if (mode == 0 || mode == 1) {
        // LDS roundtrip: tile [128 rows][NTILE cols] bf16 in Sbuf base
        __syncthreads();
        #pragma unroll
        for (int mf = 0; mf < MF; ++mf) {
            #pragma unroll
            for (int nf = 0; nf < 4; ++nf) {
                int tcol = wn + nf*16 + ln;
                float bv = bias[n0 + tcol];
                #pragma unroll
                for (int r = 0; r < 4; ++r) {
                    int trow = wm + mf*16 + g*4 + r;
                    *(unsigned short*)(Sbuf + trow * (NTILE*2) + tcol * 2) =
                        __builtin_bit_cast(unsigned short,
                            __float2bfloat16((acc[mf][nf][r] + bv) * scl));
                }
            }
        }
        __syncthreads();
        constexpr int TPR = NTILE / 8;           // threads per row (16B chunks)
        const int rr = tid / TPR, cc = (tid % TPR) * 8;
        #pragma unroll
        for (int it = 0; it < 128 / (256 / TPR); ++it) {
            int row = it * (256 / TPR) + rr;
            uint4 v = *(const uint4*)(Sbuf + row * (NTILE*2) + cc * 2);
            *(uint4*)((bf16*)Cout + (size_t)(m0 + row) * 1024 + n0 + cc) = v;
        }
    } else {
        // mode 3: fp32 out via 2 chunks of 32 cols (16KB each) through Sbuf
        #pragma unroll
        for (int p = 0; p < 2; ++p) {
            __syncthreads();
            #pragma unroll
            for (int mf = 0; mf < MF; ++mf) {
                #pragma unroll
                for (int j = 0; j < 2; ++j) {
                    int nf = p * 2 + j;
                    int tcol = j*16 + ln;            // 0..31 within chunk
                    float bv = bias[n0 + wn + nf*16 + ln];
                    #pragma unroll
                    for (int r = 0; r < 4; ++r) {
                        int trow = wm + mf*16 + g*4 + r;
                        *(float*)(Sbuf + trow * 128 + tcol * 4) = acc[mf][nf][r] + bv;
                    }
                }
            }
            __syncthreads();
            const int rr = tid >> 3, cc = (tid & 7) * 4;
            #pragma unroll
            for (int it = 0; it < 4; ++it) {
                int row = it * 32 + rr;
                uint4 v = *(const uint4*)(Sbuf + row * 128 + cc * 4);
                *(uint4*)((float*)Cout + (size_t)(m0 + row) * 1024 + n0 + p*32 + cc) = v;
            }
        }
    }
}

// ---------------- flash attention (r8 best config) ----------------
// qh: [B*S][1024] bf16 pre-scaled by log2e/sqrt(2); kh: [B*S][1024] bf16;
// vt: [B][H][64][2048] bf16; aout: [B*S][1024] bf16.
// 128 q/block, 4 waves x 32 q. KV staged 128 rows/iter (dbuf, 64KB LDS).
// Phase order per iter: QK_A,QK_B (MFMA) -> SM_A,SM_B (VALU/TRANS) -> PV_A,PV_B.
__global__ __launch_bounds__(256, 2)
void attn_kernel(const bf16* __restrict__ qh, const bf16* __restrict__ kh,
                 const bf16* __restrict__ vt, bf16* __restrict__ aout)
{
    __shared__ __align__(16) bf16 Kls[2][128 * 64];
    __shared__ __align__(16) bf16 Vls[2][64 * 128];
    const int f = blockIdx.x;
    const int xcd = f & 7, s = f >> 3, i = s & 15, ghi = s >> 4;
    const int bh = xcd + 8 * ghi;
    const int b = bh >> 4, h = bh & 15;
    const int q0 = i * 128;

    const int tid = threadIdx.x;
    const int wave = tid >> 6, lane = tid & 63;
    const int g = lane >> 4, ln = lane & 15;
    const int srow = lane >> 3;
    const int scol = ((lane & 7) * 16) ^ ((srow & 7) << 4);
    const int lnsw = (ln & 7) << 4;

    const bf16* kbase = kh + (size_t)(b * 2048) * 1024 + h * 64;
    const bf16* vbase = vt + (size_t)bh * 64 * 2048;

    const int vrow_in = lane >> 4;
    const int vcol16 = lane & 15;

    bf16x8 qf[2][2];
    #pragma unroll
    for (int nf = 0; nf < 2; ++nf) {
        const bf16* qrow = qh + (size_t)(b*2048 + q0 + wave*32 + nf*16 + ln) * 1024 + h*64;
        qf[nf][0] = *(const bf16x8*)(qrow + g*8);
        qf[nf][1] = *(const bf16x8*)(qrow + 32 + g*8);
    }

    auto stageKV = [&](int kv0, int buf) {
        #pragma unroll
        for (int c2 = 0; c2 < 4; ++c2) {
            int c = wave * 4 + c2;
            int krow = c * 8 + srow;
            gload_lds16((const char*)(kbase + (size_t)(kv0 + krow) * 1024) + scol,
                        (char*)&Kls[buf][0] + c * 1024);
        }
        #pragma unroll
        for (int c2 = 0; c2 < 4; ++c2) {
            int c = wave * 4 + c2;
            int vrow = c * 4 + vrow_in;
            int sc16 = vcol16 ^ (vrow & 15);
            gload_lds16((const char*)(vbase + (size_t)vrow * 2048 + kv0) + sc16 * 16,
                        (char*)&Vls[buf][0] + c * 1024);
        }
    };

    stageKV(0, 0);

    f32x4 oacc[4][2] = {};
    f32x4 lacc[2] = {};
    union PU { unsigned u[4]; bf16x8 v; };
    PU ones;
    ones.u[0] = ones.u[1] = ones.u[2] = ones.u[3] = 0x3F803F80u;  // bf16 1.0 x2

    for (int t = 0; t < 16; ++t) {
        const int cur = t & 1;
        if (t < 15) {
            stageKV((t + 1) * 128, cur ^ 1);
            asm volatile("s_waitcnt vmcnt(8)\n\ts_barrier" ::: "memory");
        } else {
            asm volatile("s_waitcnt vmcnt(0)\n\ts_barrier" ::: "memory");
        }
        __builtin_amdgcn_sched_barrier(0);

        const char* Kc = (const char*)&Kls[cur][0];
        const char* Vc = (const char*)&Vls[cur][0];

        // ---- QK for both halves (independent MFMA chains) ----
        f32x4 sacA[4][2] = {}, sacB[4][2] = {};
        __builtin_amdgcn_s_setprio(1);
        #pragma unroll
        for (int kk = 0; kk < 2; ++kk) {
            bf16x8 kf[4];
            #pragma unroll
            for (int mf = 0; mf < 4; ++mf)
                kf[mf] = *(const bf16x8*)(Kc + (mf*16 + ln) * 128 + ((kk*64 + g*16) ^ lnsw));
            #pragma unroll
            for (int mf = 0; mf < 4; ++mf)
                #pragma unroll
                for (int nf = 0; nf < 2; ++nf)
                    sacA[mf][nf] = __builtin_amdgcn_mfma_f32_16x16x32_bf16(kf[mf], qf[nf][kk], sacA[mf][nf], 0, 0, 0);
        }
        #pragma unroll
        for (int kk = 0; kk < 2; ++kk) {
            bf16x8 kf[4];
            #pragma unroll
            for (int mf = 0; mf < 4; ++mf)
                kf[mf] = *(const bf16x8*)(Kc + (64 + mf*16 + ln) * 128 + ((kk*64 + g*16) ^ lnsw));
            #pragma unroll
            for (int mf = 0; mf < 4; ++mf)
                #pragma unroll
                for (int nf = 0; nf < 2; ++nf)
                    sacB[mf][nf] = __builtin_amdgcn_mfma_f32_16x16x32_bf16(kf[mf], qf[nf][kk], sacB[mf][nf], 0, 0, 0);
        }
        __builtin_amdgcn_s_setprio(0);

        // ---- softmax for BOTH halves (VALU/TRANS) ----
        PU pfh[2][2][2];   // [ha][nf][kk]
        #pragma unroll
        for (int ha = 0; ha < 2; ++ha) {
            f32x4 (&sac)[4][2] = ha ? sacB : sacA;
            #pragma unroll
            for (int nf = 0; nf < 2; ++nf) {
                unsigned w[4][2];
                #pragma unroll
                for (int mf = 0; mf < 4; ++mf) {
                    float e0 = fexp2(sac[mf][nf][0]);
                    float e1 = fexp2(sac[mf][nf][1]);
                    float e2 = fexp2(sac[mf][nf][2]);
                    float e3 = fexp2(sac[mf][nf][3]);
                    w[mf][0] = cvtpk(e0, e1);
                    w[mf][1] = cvtpk(e2, e3);
                }
                #pragma unroll
                for (int kk = 0; kk < 2; ++kk) {
                    #pragma unroll
                    for (int rp = 0; rp < 2; ++rp) {
                        unsigned a = w[2*kk][rp], bb = w[2*kk + 1][rp];
                        pls32(a, bb);
                        pls16(a, bb);
                        pfh[ha][nf][kk].u[rp] = a;
                        pfh[ha][nf][kk].u[2 + rp] = bb;
                    }
                }
            }
        }

        // ---- PV for both halves ----
        __builtin_amdgcn_s_setprio(1);
        #pragma unroll
        for (int ha = 0; ha < 2; ++ha) {
            #pragma unroll
            for (int kk = 0; kk < 2; ++kk) {
                bf16x8 vf[4];
                #pragma unroll
                for (int mf = 0; mf < 4; ++mf)
                    vf[mf] = *(const bf16x8*)(Vc + (mf*16 + ln) * 256 + (((ha*8 + kk*4 + g) ^ ln) << 4));
                #pragma unroll
                for (int nf = 0; nf < 2; ++nf)
                    lacc[nf] = __builtin_amdgcn_mfma_f32_16x16x32_bf16(ones.v, pfh[ha][nf][kk].v, lacc[nf], 0, 0, 0);
                #pragma unroll
                for (int mf = 0; mf < 4; ++mf)
                    #pragma unroll
                    for (int nf = 0; nf < 2; ++nf)
                        oacc[mf][nf] = __builtin_amdgcn_mfma_f32_16x16x32_bf16(vf[mf], pfh[ha][nf][kk].v, oacc[mf][nf], 0, 0, 0);
            }
        }
        __builtin_amdgcn_s_setprio(0);
        __builtin_amdgcn_sched_barrier(0);
        asm volatile("s_barrier" ::: "memory");
    }

    #pragma unroll
    for (int nf = 0; nf < 2; ++nf) {
        float inv = 1.0f / lacc[nf][0];
        int q = q0 + wave*32 + nf*16 + ln;
        bf16* orow = aout + (size_t)(b*2048 + q) * 1024 + h * 64;
        #pragma unroll
        for (int mf = 0; mf < 4; ++mf) {
            *(uint2*)(orow + mf*16 + g*4) = make_uint2(
                pack2bf(oacc[mf][nf][0] * inv, oacc[mf][nf][1] * inv),
                pack2bf(oacc[mf][nf][2] * inv, oacc[mf][nf][3] * inv));
        }
    }
}

// ---------------- host ----------------
extern "C" void kernel_launch(void* const* d_in, const int* in_sizes, int n_in,
                              void* d_out, int out_size, void* d_ws, size_t ws_size,
                              hipStream_t stream)
{
    const float* Q  = (const float*)d_in[0];
    const float* K  = (const float*)d_in[1];
    const float* V  = (const float*)d_in[2];
    const float* Wq = (const float*)d_in[3];
    const float* bq = (const float*)d_in[4];
    const float* Wk = (const float*)d_in[5];
    const float* bk = (const float*)d_in[6];
    const float* Wv = (const float*)d_in[7];
    const float* bv = (const float*)d_in[8];
    const float* Wo = (const float*)d_in[9];
    const float* bo = (const float*)d_in[10];

    char* ws = (char*)d_ws;
    const size_t MB = 1024 * 1024;
    bf16* Qbf  = (bf16*)(ws + 0);
    bf16* Kbf  = (bf16*)(ws + 8*MB);
    bf16* Vbf  = (bf16*)(ws + 16*MB);
    bf16* WqT  = (bf16*)(ws + 24*MB);
    bf16* WkT  = (bf16*)(ws + 26*MB);
    bf16* WvT  = (bf16*)(ws + 28*MB);
    bf16* WoT  = (bf16*)(ws + 30*MB);
    bf16* qhp  = (bf16*)(ws + 32*MB);
    bf16* khp  = (bf16*)(ws + 40*MB);
    bf16* vtp  = (bf16*)(ws + 48*MB);
    bf16* aout = (bf16*)(ws + 0);      // alias Qbf (dead after projections)

    const int n4 = (2 * 2048 * 1024) / 4;
    prep_kernel<<<dim3(1024, 1, 7), 256, 0, stream>>>(Q, K, V, Qbf, Kbf, Vbf,
                                                      Wq, Wk, Wv, Wo, WqT, WkT, WvT, WoT, n4);

    gemm_bt<128><<<768, 256, 0, stream>>>(Qbf, Kbf, Vbf, WqT, WkT, WvT,
                                          bq, bk, bv, qhp, khp, vtp, 0);

    attn_kernel<<<512, 256, 0, stream>>>(qhp, khp, vtp, aout);

    gemm_bt<64><<<512, 256, 0, stream>>>(aout, aout, aout, WoT, WoT, WoT,
                                         bo, bo, bo, d_out, d_out, d_out, 3);
}

// Round 17
// 104.306 us; speedup vs baseline: 1.1193x; 1.0071x over previous
//
#include <hip/hip_runtime.h>
#include <hip/hip_bf16.h>

// MHA layer B=2, S=2048, DM=1024, H=16, DK=DV=64 on gfx950.
// prep (conv fp32->bf16 + weight transpose, 1 launch) -> 3 proj GEMMs
// (m97 + dbuf, SINGLE barrier/K-step: stage issued after barrier) ->
// flash attention (r8 phase order, SINGLE barrier/iter) -> out GEMM (128x64).
// Single-barrier safety: at iter t's barrier every wave has executed iter t-1's
// MFMAs; their lgkmcnt waits imply all ds_reads of buf[cur^1] already sampled,
// so post-barrier writes into buf[cur^1] cannot race readers.

using bf16 = __hip_bfloat16;
typedef __attribute__((ext_vector_type(4))) float f32x4;
typedef __attribute__((ext_vector_type(8))) short bf16x8;

__device__ __forceinline__ void gload_lds16(const void* gsrc, void* ldst) {
    __builtin_amdgcn_global_load_lds(
        (const __attribute__((address_space(1))) void*)gsrc,
        (__attribute__((address_space(3))) void*)ldst,
        16, 0, 0);
}

__device__ __forceinline__ float fexp2(float x) {
    float r; asm("v_exp_f32 %0, %1" : "=v"(r) : "v"(x)); return r;
}

__device__ __forceinline__ unsigned cvtpk(float a, float b) {
    unsigned d; asm("v_cvt_pk_bf16_f32 %0, %1, %2" : "=v"(d) : "v"(a), "v"(b));
    return d;
}

__device__ __forceinline__ void pls32(unsigned &a, unsigned &b) {
    asm("v_permlane32_swap_b32 %0, %1" : "+v"(a), "+v"(b));
}
__device__ __forceinline__ void pls16(unsigned &a, unsigned &b) {
    asm("v_permlane16_swap_b32 %0, %1" : "+v"(a), "+v"(b));
}

__device__ __forceinline__ unsigned pack2bf(float a, float b) {
    unsigned short ua = __builtin_bit_cast(unsigned short, __float2bfloat16(a));
    unsigned short ub = __builtin_bit_cast(unsigned short, __float2bfloat16(b));
    return (unsigned)ua | ((unsigned)ub << 16);
}

// ---------------- prep: z=0..2 conv fp32->bf16 (grid-stride), z=3..6 transpose ----------------
__global__ void prep_kernel(const float* __restrict__ X0, const float* __restrict__ X1,
                            const float* __restrict__ X2,
                            bf16* __restrict__ O0, bf16* __restrict__ O1, bf16* __restrict__ O2,
                            const float* __restrict__ W0, const float* __restrict__ W1,
                            const float* __restrict__ W2, const float* __restrict__ W3,
                            bf16* __restrict__ T0, bf16* __restrict__ T1,
                            bf16* __restrict__ T2, bf16* __restrict__ T3,
                            int n4) {
    const int z = blockIdx.z;
    if (z < 3) {
        const float* in = z == 0 ? X0 : (z == 1 ? X1 : X2);
        bf16* out = z == 0 ? O0 : (z == 1 ? O1 : O2);
        int idx = blockIdx.x * blockDim.x + threadIdx.x;
        int stride = gridDim.x * blockDim.x;
        for (int i = idx; i < n4; i += stride) {
            float4 v = reinterpret_cast<const float4*>(in)[i];
            reinterpret_cast<uint2*>(out)[i] = make_uint2(pack2bf(v.x, v.y), pack2bf(v.z, v.w));
        }
    } else {
        const int w = z - 3;
        const float* W = w == 0 ? W0 : (w == 1 ? W1 : (w == 2 ? W2 : W3));
        bf16* WT = w == 0 ? T0 : (w == 1 ? T1 : (w == 2 ? T2 : T3));
        __shared__ float t[32][33];
        int bx = (blockIdx.x & 31) * 32, by = (blockIdx.x >> 5) * 32;
        int x = threadIdx.x & 31, y = threadIdx.x >> 5;
        #pragma unroll
        for (int i = 0; i < 4; ++i)
            t[y + 8*i][x] = W[(size_t)(by + y + 8*i) * 1024 + bx + x];
        __syncthreads();
        #pragma unroll
        for (int i = 0; i < 4; ++i)
            WT[(size_t)(bx + y + 8*i) * 1024 + by + x] = __float2bfloat16(t[x][y + 8*i]);
    }
}

// ---------------- GEMM: C[4096,NTOT] = A[4096,1024] @ BT^T + bias ----------------
// m97 + dbuf, single barrier per K-step (stage issued post-barrier).
// Epilogues: mode 0/1 bf16 via LDS-roundtrip coalesced uint4 stores; mode 2
// (Vt[b][h][dv][s]) packed uint2; mode 3 fp32 via 2-chunk LDS.
template<int NTILE>
__global__ __launch_bounds__(256, (NTILE == 128) ? 2 : 3)
void gemm_bt(const bf16* __restrict__ A0, const bf16* __restrict__ A1, const bf16* __restrict__ A2,
             const bf16* __restrict__ B0, const bf16* __restrict__ B1, const bf16* __restrict__ B2,
             const float* __restrict__ bi0, const float* __restrict__ bi1, const float* __restrict__ bi2,
             void* __restrict__ O0, void* __restrict__ O1, void* __restrict__ O2,
             int mode_base)
{
    const int f = blockIdx.x;
    int x, y, z;
    if (NTILE == 128) {
        const int s = f >> 3;
        y = s & 7;
        const int t = (f & 7) + 8 * (s >> 3);
        x = t & 31; z = t >> 5;
    } else {
        const int s = f >> 3;
        y = s & 15;
        x = (f & 7) + 8 * (s >> 4);
        z = 0;
    }
    const bf16* A  = z == 0 ? A0 : (z == 1 ? A1 : A2);
    const bf16* BT = z == 0 ? B0 : (z == 1 ? B1 : B2);
    const float* bias = z == 0 ? bi0 : (z == 1 ? bi1 : bi2);
    void* Cout = z == 0 ? O0 : (z == 1 ? O1 : O2);
    const int mode = mode_base + z;

    constexpr int ABYTES = 16384;
    constexpr int BBYTES = NTILE * 128;
    constexpr int BUFB   = ABYTES + BBYTES;
    __shared__ __align__(16) char Sbuf[2 * BUFB];
    constexpr int MF = (NTILE == 128) ? 4 : 2;
    const int tid = threadIdx.x;
    const int wave = tid >> 6, lane = tid & 63;
    const int g = lane >> 4, ln = lane & 15;
    const int m0 = x * 128, n0 = y * NTILE;
    const int wm = (NTILE == 128) ? (wave >> 1) * 64 : wave * 32;
    const int wn = (NTILE == 128) ? (wave & 1) * 64 : 0;
    const int lnsw = (ln & 7) << 4;

    auto stage = [&](int k0, int buf) {
        char* Ab = Sbuf + buf * BUFB;
        char* Bb = Ab + ABYTES;
        #pragma unroll
        for (int rd = 0; rd < 4; ++rd) {
            int row = rd * 32 + (tid >> 3);
            int src = ((tid & 7) * 16) ^ (((tid >> 3) & 7) << 4);
            gload_lds16((const char*)(A + (size_t)(m0 + row) * 1024 + k0) + src,
                        Ab + rd * 4096 + tid * 16);
        }
        #pragma unroll
        for (int rd = 0; rd < NTILE / 32; ++rd) {
            int row = rd * 32 + (tid >> 3);
            int src = ((tid & 7) * 16) ^ (((tid >> 3) & 7) << 4);
            gload_lds16((const char*)(BT + (size_t)(n0 + row) * 1024 + k0) + src,
                        Bb + rd * 4096 + tid * 16);
        }
    };

    f32x4 acc[MF][4] = {};
    stage(0, 0);

    for (int k = 0; k < 16; ++k) {
        const int cur = k & 1;
        asm volatile("s_waitcnt vmcnt(0)\n\ts_barrier" ::: "memory");
        __builtin_amdgcn_sched_barrier(0);
        if (k < 15) stage((k + 1) * 64, cur ^ 1);   // post-barrier: safe (see header)
        __builtin_amdgcn_sched_barrier(0);

        const char* Ab = Sbuf + cur * BUFB;
        const char* Bb = Ab + ABYTES;
        #pragma unroll
        for (int kk = 0; kk < 2; ++kk) {
            bf16x8 af[MF], bfr[4];
            #pragma unroll
            for (int mf = 0; mf < MF; ++mf)
                af[mf] = *(const bf16x8*)(Ab + (wm + mf*16 + ln) * 128 + ((kk*64 + g*16) ^ lnsw));
            #pragma unroll
            for (int nf = 0; nf < 4; ++nf)
                bfr[nf] = *(const bf16x8*)(Bb + (wn + nf*16 + ln) * 128 + ((kk*64 + g*16) ^ lnsw));
            #pragma unroll
            for (int mf = 0; mf < MF; ++mf)
                #pragma unroll
                for (int nf = 0; nf < 4; ++nf)
                    acc[mf][nf] = __builtin_amdgcn_mfma_f32_16x16x32_bf16(af[mf], bfr[nf], acc[mf][nf], 0, 0, 0);
        }
    }

    const float scl = (mode == 0) ? (0.70710678118654752f * 1.44269504088896340f) : 1.0f;

    if (mode == 2) {
        // Vt[b][h][dv][s]: fragment's 4 values are 4 consecutive s at fixed dv -> uint2
        #pragma unroll
        for (int mf = 0; mf < MF; ++mf) {
            #pragma unroll
            for (int nf = 0; nf < 4; ++nf) {
                int col = n0 + wn + nf*16 + ln;
                float bv = bias[col];
                int row0 = m0 + wm + mf*16 + g*4;
                int b = row0 >> 11, ss = row0 & 2047;
                int hh = col >> 6, dv = col & 63;
                bf16* dst = (bf16*)Cout + (((size_t)(b*16 + hh) * 64 + dv) << 11) + ss;
                *(uint2*)dst = make_uint2(
                    pack2bf(acc[mf][nf][0] + bv, acc[mf][nf][1] + bv),
                    pack2bf(acc[mf][nf][2] + bv, acc[mf][nf][3] + bv));
            }
        }
    } else if (mode == 0 || mode == 1) {
        // LDS roundtrip: tile [128 rows][NTILE cols] bf16 in Sbuf base
        __syncthreads();
        #pragma unroll
        for (int mf = 0; mf < MF; ++mf) {
            #pragma unroll
            for (int nf = 0; nf < 4; ++nf) {
                int tcol = wn + nf*16 + ln;
                float bv = bias[n0 + tcol];
                #pragma unroll
                for (int r = 0; r < 4; ++r) {
                    int trow = wm + mf*16 + g*4 + r;
                    *(unsigned short*)(Sbuf + trow * (NTILE*2) + tcol * 2) =
                        __builtin_bit_cast(unsigned short,
                            __float2bfloat16((acc[mf][nf][r] + bv) * scl));
                }
            }
        }
        __syncthreads();
        constexpr int TPR = NTILE / 8;           // threads per row (16B chunks)
        const int rr = tid / TPR, cc = (tid % TPR) * 8;
        #pragma unroll
        for (int it = 0; it < 128 / (256 / TPR); ++it) {
            int row = it * (256 / TPR) + rr;
            uint4 v = *(const uint4*)(Sbuf + row * (NTILE*2) + cc * 2);
            *(uint4*)((bf16*)Cout + (size_t)(m0 + row) * 1024 + n0 + cc) = v;
        }
    } else {
        // mode 3: fp32 out via 2 chunks of 32 cols (16KB each) through Sbuf
        #pragma unroll
        for (int p = 0; p < 2; ++p) {
            __syncthreads();
            #pragma unroll
            for (int mf = 0; mf < MF; ++mf) {
                #pragma unroll
                for (int j = 0; j < 2; ++j) {
                    int nf = p * 2 + j;
                    int tcol = j*16 + ln;            // 0..31 within chunk
                    float bv = bias[n0 + wn + nf*16 + ln];
                    #pragma unroll
                    for (int r = 0; r < 4; ++r) {
                        int trow = wm + mf*16 + g*4 + r;
                        *(float*)(Sbuf + trow * 128 + tcol * 4) = acc[mf][nf][r] + bv;
                    }
                }
            }
            __syncthreads();
            const int rr = tid >> 3, cc = (tid & 7) * 4;
            #pragma unroll
            for (int it = 0; it < 4; ++it) {
                int row = it * 32 + rr;
                uint4 v = *(const uint4*)(Sbuf + row * 128 + cc * 4);
                *(uint4*)((float*)Cout + (size_t)(m0 + row) * 1024 + n0 + p*32 + cc) = v;
            }
        }
    }
}

// ---------------- flash attention (r8 phase order, single barrier/iter) ----------------
// qh: [B*S][1024] bf16 pre-scaled by log2e/sqrt(2); kh: [B*S][1024] bf16;
// vt: [B][H][64][2048] bf16; aout: [B*S][1024] bf16.
// 128 q/block, 4 waves x 32 q. KV staged 128 rows/iter (dbuf, 64KB LDS).
// Per iter: vmcnt(0)+barrier -> stage(t+1) -> QK_A,QK_B -> SM_A,SM_B -> PV_A,PV_B.
__global__ __launch_bounds__(256, 2)
void attn_kernel(const bf16* __restrict__ qh, const bf16* __restrict__ kh,
                 const bf16* __restrict__ vt, bf16* __restrict__ aout)
{
    __shared__ __align__(16) bf16 Kls[2][128 * 64];
    __shared__ __align__(16) bf16 Vls[2][64 * 128];
    const int f = blockIdx.x;
    const int xcd = f & 7, s = f >> 3, i = s & 15, ghi = s >> 4;
    const int bh = xcd + 8 * ghi;
    const int b = bh >> 4, h = bh & 15;
    const int q0 = i * 128;

    const int tid = threadIdx.x;
    const int wave = tid >> 6, lane = tid & 63;
    const int g = lane >> 4, ln = lane & 15;
    const int srow = lane >> 3;
    const int scol = ((lane & 7) * 16) ^ ((srow & 7) << 4);
    const int lnsw = (ln & 7) << 4;

    const bf16* kbase = kh + (size_t)(b * 2048) * 1024 + h * 64;
    const bf16* vbase = vt + (size_t)bh * 64 * 2048;

    const int vrow_in = lane >> 4;
    const int vcol16 = lane & 15;

    bf16x8 qf[2][2];
    #pragma unroll
    for (int nf = 0; nf < 2; ++nf) {
        const bf16* qrow = qh + (size_t)(b*2048 + q0 + wave*32 + nf*16 + ln) * 1024 + h*64;
        qf[nf][0] = *(const bf16x8*)(qrow + g*8);
        qf[nf][1] = *(const bf16x8*)(qrow + 32 + g*8);
    }

    auto stageKV = [&](int kv0, int buf) {
        #pragma unroll
        for (int c2 = 0; c2 < 4; ++c2) {
            int c = wave * 4 + c2;
            int krow = c * 8 + srow;
            gload_lds16((const char*)(kbase + (size_t)(kv0 + krow) * 1024) + scol,
                        (char*)&Kls[buf][0] + c * 1024);
        }
        #pragma unroll
        for (int c2 = 0; c2 < 4; ++c2) {
            int c = wave * 4 + c2;
            int vrow = c * 4 + vrow_in;
            int sc16 = vcol16 ^ (vrow & 15);
            gload_lds16((const char*)(vbase + (size_t)vrow * 2048 + kv0) + sc16 * 16,
                        (char*)&Vls[buf][0] + c * 1024);
        }
    };

    stageKV(0, 0);

    f32x4 oacc[4][2] = {};
    f32x4 lacc[2] = {};
    union PU { unsigned u[4]; bf16x8 v; };
    PU ones;
    ones.u[0] = ones.u[1] = ones.u[2] = ones.u[3] = 0x3F803F80u;  // bf16 1.0 x2

    for (int t = 0; t < 16; ++t) {
        const int cur = t & 1;
        asm volatile("s_waitcnt vmcnt(0)\n\ts_barrier" ::: "memory");
        __builtin_amdgcn_sched_barrier(0);
        if (t < 15) stageKV((t + 1) * 128, cur ^ 1);   // post-barrier: safe (see header)
        __builtin_amdgcn_sched_barrier(0);

        const char* Kc = (const char*)&Kls[cur][0];
        const char* Vc = (const char*)&Vls[cur][0];

        // ---- QK for both halves (independent MFMA chains) ----
        f32x4 sacA[4][2] = {}, sacB[4][2] = {};
        __builtin_amdgcn_s_setprio(1);
        #pragma unroll
        for (int kk = 0; kk < 2; ++kk) {
            bf16x8 kf[4];
            #pragma unroll
            for (int mf = 0; mf < 4; ++mf)
                kf[mf] = *(const bf16x8*)(Kc + (mf*16 + ln) * 128 + ((kk*64 + g*16) ^ lnsw));
            #pragma unroll
            for (int mf = 0; mf < 4; ++mf)
                #pragma unroll
                for (int nf = 0; nf < 2; ++nf)
                    sacA[mf][nf] = __builtin_amdgcn_mfma_f32_16x16x32_bf16(kf[mf], qf[nf][kk], sacA[mf][nf], 0, 0, 0);
        }
        #pragma unroll
        for (int kk = 0; kk < 2; ++kk) {
            bf16x8 kf[4];
            #pragma unroll
            for (int mf = 0; mf < 4; ++mf)
                kf[mf] = *(const bf16x8*)(Kc + (64 + mf*16 + ln) * 128 + ((kk*64 + g*16) ^ lnsw));
            #pragma unroll
            for (int mf = 0; mf < 4; ++mf)
                #pragma unroll
                for (int nf = 0; nf < 2; ++nf)
                    sacB[mf][nf] = __builtin_amdgcn_mfma_f32_16x16x32_bf16(kf[mf], qf[nf][kk], sacB[mf][nf], 0, 0, 0);
        }
        __builtin_amdgcn_s_setprio(0);

        // ---- softmax for BOTH halves (VALU/TRANS) ----
        PU pfh[2][2][2];   // [ha][nf][kk]
        #pragma unroll
        for (int ha = 0; ha < 2; ++ha) {
            f32x4 (&sac)[4][2] = ha ? sacB : sacA;
            #pragma unroll
            for (int nf = 0; nf < 2; ++nf) {
                unsigned w[4][2];
                #pragma unroll
                for (int mf = 0; mf < 4; ++mf) {
                    float e0 = fexp2(sac[mf][nf][0]);
                    float e1 = fexp2(sac[mf][nf][1]);
                    float e2 = fexp2(sac[mf][nf][2]);
                    float e3 = fexp2(sac[mf][nf][3]);
                    w[mf][0] = cvtpk(e0, e1);
                    w[mf][1] = cvtpk(e2, e3);
                }
                #pragma unroll
                for (int kk = 0; kk < 2; ++kk) {
                    #pragma unroll
                    for (int rp = 0; rp < 2; ++rp) {
                        unsigned a = w[2*kk][rp], bb = w[2*kk + 1][rp];
                        pls32(a, bb);
                        pls16(a, bb);
                        pfh[ha][nf][kk].u[rp] = a;
                        pfh[ha][nf][kk].u[2 + rp] = bb;
                    }
                }
            }
        }

        // ---- PV for both halves ----
        __builtin_amdgcn_s_setprio(1);
        #pragma unroll
        for (int ha = 0; ha < 2; ++ha) {
            #pragma unroll
            for (int kk = 0; kk < 2; ++kk) {
                bf16x8 vf[4];
                #pragma unroll
                for (int mf = 0; mf < 4; ++mf)
                    vf[mf] = *(const bf16x8*)(Vc + (mf*16 + ln) * 256 + (((ha*8 + kk*4 + g) ^ ln) << 4));
                #pragma unroll
                for (int nf = 0; nf < 2; ++nf)
                    lacc[nf] = __builtin_amdgcn_mfma_f32_16x16x32_bf16(ones.v, pfh[ha][nf][kk].v, lacc[nf], 0, 0, 0);
                #pragma unroll
                for (int mf = 0; mf < 4; ++mf)
                    #pragma unroll
                    for (int nf = 0; nf < 2; ++nf)
                        oacc[mf][nf] = __builtin_amdgcn_mfma_f32_16x16x32_bf16(vf[mf], pfh[ha][nf][kk].v, oacc[mf][nf], 0, 0, 0);
            }
        }
        __builtin_amdgcn_s_setprio(0);
    }

    #pragma unroll
    for (int nf = 0; nf < 2; ++nf) {
        float inv = 1.0f / lacc[nf][0];
        int q = q0 + wave*32 + nf*16 + ln;
        bf16* orow = aout + (size_t)(b*2048 + q) * 1024 + h * 64;
        #pragma unroll
        for (int mf = 0; mf < 4; ++mf) {
            *(uint2*)(orow + mf*16 + g*4) = make_uint2(
                pack2bf(oacc[mf][nf][0] * inv, oacc[mf][nf][1] * inv),
                pack2bf(oacc[mf][nf][2] * inv, oacc[mf][nf][3] * inv));
        }
    }
}

// ---------------- host ----------------
extern "C" void kernel_launch(void* const* d_in, const int* in_sizes, int n_in,
                              void* d_out, int out_size, void* d_ws, size_t ws_size,
                              hipStream_t stream)
{
    const float* Q  = (const float*)d_in[0];
    const float* K  = (const float*)d_in[1];
    const float* V  = (const float*)d_in[2];
    const float* Wq = (const float*)d_in[3];
    const float* bq = (const float*)d_in[4];
    const float* Wk = (const float*)d_in[5];
    const float* bk = (const float*)d_in[6];
    const float* Wv = (const float*)d_in[7];
    const float* bv = (const float*)d_in[8];
    const float* Wo = (const float*)d_in[9];
    const float* bo = (const float*)d_in[10];

    char* ws = (char*)d_ws;
    const size_t MB = 1024 * 1024;
    bf16* Qbf  = (bf16*)(ws + 0);
    bf16* Kbf  = (bf16*)(ws + 8*MB);
    bf16* Vbf  = (bf16*)(ws + 16*MB);
    bf16* WqT  = (bf16*)(ws + 24*MB);
    bf16* WkT  = (bf16*)(ws + 26*MB);
    bf16* WvT  = (bf16*)(ws + 28*MB);
    bf16* WoT  = (bf16*)(ws + 30*MB);
    bf16* qhp  = (bf16*)(ws + 32*MB);
    bf16* khp  = (bf16*)(ws + 40*MB);
    bf16* vtp  = (bf16*)(ws + 48*MB);
    bf16* aout = (bf16*)(ws + 0);      // alias Qbf (dead after projections)

    const int n4 = (2 * 2048 * 1024) / 4;
    prep_kernel<<<dim3(1024, 1, 7), 256, 0, stream>>>(Q, K, V, Qbf, Kbf, Vbf,
                                                      Wq, Wk, Wv, Wo, WqT, WkT, WvT, WoT, n4);

    gemm_bt<128><<<768, 256, 0, stream>>>(Qbf, Kbf, Vbf, WqT, WkT, WvT,
                                          bq, bk, bv, qhp, khp, vtp, 0);

    attn_kernel<<<512, 256, 0, stream>>>(qhp, khp, vtp, aout);

    gemm_bt<64><<<512, 256, 0, stream>>>(aout, aout, aout, WoT, WoT, WoT,
                                         bo, bo, bo, d_out, d_out, d_out, 3);
}